// Round 7
// baseline (3153.806 us; speedup 1.0000x reference)
//
#include <hip/hip_runtime.h>
#include <cstdint>
#include <cstddef>

#define NPTS 8192
#define MCTR 2048
#define BATCH 4
#define KNB 32

// ---- u64 wave max via DPP (identity 0), broadcast from lane 63 ----
__device__ __forceinline__ unsigned long long wave_max_key(unsigned long long k) {
#define STEPK(ctrl, rmask, bmask)                                                         \
  {                                                                                       \
    int lo_ = __builtin_amdgcn_update_dpp(0, (int)(unsigned)(k & 0xffffffffull), ctrl,    \
                                          rmask, bmask, false);                           \
    int hi_ = __builtin_amdgcn_update_dpp(0, (int)(unsigned)(k >> 32), ctrl, rmask,       \
                                          bmask, false);                                  \
    unsigned long long o_ =                                                               \
        ((unsigned long long)(unsigned)hi_ << 32) | (unsigned)lo_;                        \
    k = k > o_ ? k : o_;                                                                  \
  }
  STEPK(0x111, 0xf, 0xf)  // row_shr:1
  STEPK(0x112, 0xf, 0xf)  // row_shr:2
  STEPK(0x114, 0xf, 0xf)  // row_shr:4
  STEPK(0x118, 0xf, 0xf)  // row_shr:8
  STEPK(0x142, 0xa, 0xf)  // row_bcast:15
  STEPK(0x143, 0xc, 0xf)  // row_bcast:31
#undef STEPK
  int lo = __builtin_amdgcn_readlane((int)(unsigned)(k & 0xffffffffull), 63);
  int hi = __builtin_amdgcn_readlane((int)(unsigned)(k >> 32), 63);
  return ((unsigned long long)(unsigned)hi << 32) | (unsigned)lo;
}

__device__ __forceinline__ unsigned long long u64max(unsigned long long a,
                                                     unsigned long long b) {
  return a > b ? a : b;
}

// ---------- feature transpose (B,32,N) -> (B,N,32) ----------
__global__ __launch_bounds__(256) void featT_kernel(const float* __restrict__ feats,
                                                    float* __restrict__ featT) {
  const int bn = blockIdx.x;
  const int b = bn >> 8;
  const int n0 = (bn & 255) * 32;
  __shared__ float tile[32][33];
  const int tx = threadIdx.x & 31, ty = threadIdx.x >> 5;
  const float* src = feats + (size_t)b * 32 * NPTS;
#pragma unroll
  for (int s = 0; s < 4; ++s) {
    int f = ty + 8 * s;
    tile[f][tx] = src[(size_t)f * NPTS + n0 + tx];
  }
  __syncthreads();
  float* dst = featT + ((size_t)b * NPTS + n0) * 32;
#pragma unroll
  for (int s = 0; s < 4; ++s) {
    int n = ty + 8 * s;
    dst[n * 32 + tx] = tile[tx][n];
  }
}

// ---------- weight transpose ----------
__global__ __launch_bounds__(256) void prep_kernel(const float* __restrict__ W1,
                                                   const float* __restrict__ W2,
                                                   const float* __restrict__ W3,
                                                   float* __restrict__ Wt) {
  const int t = blockIdx.x * 256 + threadIdx.x;
  if (t < 2240) { int c = t >> 6, o = t & 63;  Wt[t] = W1[o * 35 + c]; }
  if (t < 4096) { int c = t >> 6, o = t & 63;  Wt[2240 + t] = W2[o * 64 + c]; }
  if (t < 8192) { int c = t >> 7, o = t & 127; Wt[6336 + t] = W3[o * 64 + c]; }
}

// ---------- counting sort by x-bucket (512 buckets), one block per batch ----------
// Also emits the bucket-start table (513 ints per batch) for windowed culling.
// Within-bucket order is nondeterministic (atomic cursors) — harmless: all
// downstream selection is keyed on (distance, ORIGINAL index), never slot order.
__global__ __launch_bounds__(512) void xsort_kernel(const float* __restrict__ coords,
                                                    float* __restrict__ sX,
                                                    float* __restrict__ sY,
                                                    float* __restrict__ sZ,
                                                    int* __restrict__ sOrig,
                                                    int* __restrict__ bstartG) {
  const int b = blockIdx.x;
  const int tid = threadIdx.x;
  const float* C = coords + (size_t)b * 3 * NPTS;
  __shared__ int h[512];
  __shared__ int cur[512];
  h[tid] = 0;
  __syncthreads();
  int bk[16];
#pragma unroll
  for (int j = 0; j < 16; ++j) {
    int i = tid + j * 512;
    float x = C[i];
    int k = (int)(x * 512.0f);
    k = k < 0 ? 0 : (k > 511 ? 511 : k);
    bk[j] = k;
    atomicAdd(&h[k], 1);
  }
  __syncthreads();
  const int cnt = h[tid];
  for (int s = 1; s < 512; s <<= 1) {  // Hillis-Steele inclusive scan
    int v = (tid >= s) ? h[tid - s] : 0;
    __syncthreads();
    h[tid] += v;
    __syncthreads();
  }
  const int start = h[tid] - cnt;  // exclusive start of bucket tid
  cur[tid] = start;
  bstartG[b * 513 + tid] = start;
  if (tid == 511) bstartG[b * 513 + 512] = h[511];  // == 8192
  __syncthreads();
  float* dX = sX + (size_t)b * NPTS;
  float* dY = sY + (size_t)b * NPTS;
  float* dZ = sZ + (size_t)b * NPTS;
  int* dO = sOrig + (size_t)b * NPTS;
#pragma unroll
  for (int j = 0; j < 16; ++j) {
    int i = tid + j * 512;
    int pos = atomicAdd(&cur[bk[j]], 1);
    dX[pos] = C[i];
    dY[pos] = C[NPTS + i];
    dZ[pos] = C[2 * NPTS + i];
    dO[pos] = i;
  }
}

// ---------- furthest point sampling: strided ownership + slot-window culling ----------
// Thread t owns slots {j*512+t : j=0..15} (STRIDED) so the contiguous x-window of
// must-update slots [lo,hi) spreads evenly over all 8 waves -> balanced critical path.
// Window via bucket table: r = sqrt(wv)*1.001 (skip provably exact: for |x-cx|>=r,
// fl(d2) >= (x-cx)^2*(1-2^-22) >= wv >= dd[p]); bucket guard +-1 absorbs fp rounding.
// Per-point state: kk[j] = (distbits<<32)|((8191-orig)<<13)|slot -> u64 max ==
// (max dist, min ORIGINAL idx) == jnp.argmax first-occurrence. No global ops in loop.
__global__ __launch_bounds__(512) void fps_kernel(const float* __restrict__ sX,
                                                  const float* __restrict__ sY,
                                                  const float* __restrict__ sZ,
                                                  const int* __restrict__ sOrig,
                                                  const int* __restrict__ bstartG,
                                                  int* __restrict__ cidx,
                                                  float* __restrict__ centers) {
  const int b = blockIdx.x;
  const int tid = threadIdx.x;
  const int wave = tid >> 6, lane = tid & 63;
  __shared__ float lC[NPTS * 3];
  __shared__ int lB[513];
  __shared__ __align__(16) unsigned long long skey[2][8];
  __shared__ int s_slot0;
  const float* gX = sX + (size_t)b * NPTS;
  const float* gY = sY + (size_t)b * NPTS;
  const float* gZ = sZ + (size_t)b * NPTS;
  const int* gO = sOrig + (size_t)b * NPTS;
  for (int i = tid; i < NPTS; i += 512) {
    float x = gX[i], y = gY[i], z = gZ[i];
    lC[3 * i] = x;
    lC[3 * i + 1] = y;
    lC[3 * i + 2] = z;
  }
  lB[tid] = bstartG[b * 513 + tid];
  if (tid == 0) lB[512] = bstartG[b * 513 + 512];
  unsigned tail[16];
  unsigned long long kk[16];
#pragma unroll
  for (int j = 0; j < 16; ++j) {
    const int slot = (j << 9) + tid;
    const int og = gO[slot];
    tail[j] = ((unsigned)(8191 - og) << 13) | (unsigned)slot;
    kk[j] = (0x7F800000ull << 32) | tail[j];  // dist = +inf
    if (og == 0) s_slot0 = slot;              // exactly one thread writes
  }
  __syncthreads();
  int slot = s_slot0;
  float cx = lC[3 * slot], cy = lC[3 * slot + 1], cz = lC[3 * slot + 2];
  float wv = __builtin_inff();
  unsigned long long kreg[4];
  if (tid == 0)  // m=0: initial point, orig 0 (dist bits unused by writeback)
    kreg[0] = ((unsigned long long)(unsigned)8191 << 13) | (unsigned)slot;
  int buf = 0;
  for (int it = 0; it < MCTR; ++it) {
    // conservative x-window of slots that could change (bucket-quantized)
    const float r = sqrtf(wv) * 1.001f;
    int bl = (int)((cx - r) * 512.0f) - 1;
    bl = bl < 0 ? 0 : (bl > 511 ? 511 : bl);
    int bh = (int)((cx + r) * 512.0f) + 1;
    bh = bh < 0 ? 0 : (bh > 511 ? 511 : bh);
    const int lo = lB[bl];
    const int hi = lB[bh + 1];
    int jlo = (lo - tid + 511) >> 9;
    jlo = jlo < 0 ? 0 : jlo;
    int jhi = (hi - tid + 511) >> 9;
    jhi = jhi > 16 ? 16 : jhi;
#pragma unroll
    for (int j = 0; j < 16; ++j) {
      if (j >= jlo && j < jhi) {
        const int s = (j << 9) + tid;
        // EXACT reference order: (dx*dx + dy*dy) + dz*dz, rn each step, no FMA
        float dx = __fsub_rn(lC[3 * s], cx);
        float dy = __fsub_rn(lC[3 * s + 1], cy);
        float dz = __fsub_rn(lC[3 * s + 2], cz);
        float d = __fadd_rn(__fadd_rn(__fmul_rn(dx, dx), __fmul_rn(dy, dy)),
                            __fmul_rn(dz, dz));
        unsigned db = __float_as_uint(d);
        if (db < (unsigned)(kk[j] >> 32))
          kk[j] = ((unsigned long long)db << 32) | tail[j];
      }
    }
    // thread key = max over 16 (branch-free tree)
    unsigned long long t0 = u64max(kk[0], kk[1]);
    unsigned long long t1 = u64max(kk[2], kk[3]);
    unsigned long long t2 = u64max(kk[4], kk[5]);
    unsigned long long t3 = u64max(kk[6], kk[7]);
    unsigned long long t4 = u64max(kk[8], kk[9]);
    unsigned long long t5 = u64max(kk[10], kk[11]);
    unsigned long long t6 = u64max(kk[12], kk[13]);
    unsigned long long t7 = u64max(kk[14], kk[15]);
    unsigned long long tkey = u64max(u64max(u64max(t0, t1), u64max(t2, t3)),
                                     u64max(u64max(t4, t5), u64max(t6, t7)));
    unsigned long long wk = wave_max_key(tkey);
    if (lane == 0) skey[buf][wave] = wk;
    __syncthreads();
    const ulonglong2* kp = (const ulonglong2*)skey[buf];
    ulonglong2 k0 = kp[0], k1 = kp[1], k2 = kp[2], k3 = kp[3];
    unsigned long long gk =
        u64max(u64max(u64max(k0.x, k0.y), u64max(k1.x, k1.y)),
               u64max(u64max(k2.x, k2.y), u64max(k3.x, k3.y)));
    if (((it + 1) >> 2) == tid) kreg[(it + 1) & 3] = gk;  // winner for m=it+1
    slot = (int)(gk & 0x1fff);
    wv = __uint_as_float((unsigned)(gk >> 32));
    cx = lC[3 * slot];
    cy = lC[3 * slot + 1];
    cz = lC[3 * slot + 2];
    buf ^= 1;
  }
  // coalesced writeback: thread t owns centers m = 4t..4t+3
#pragma unroll
  for (int r = 0; r < 4; ++r) {
    unsigned long long k = kreg[r];
    int orig = 8191 - (int)((k >> 13) & 0x1fff);
    int sl = (int)(k & 0x1fff);
    int m = 4 * tid + r;
    cidx[b * MCTR + m] = orig;
    centers[(size_t)b * 3 * MCTR + m] = lC[3 * sl];
    centers[(size_t)b * 3 * MCTR + MCTR + m] = lC[3 * sl + 1];
    centers[(size_t)b * 3 * MCTR + 2 * MCTR + m] = lC[3 * sl + 2];
  }
}

// ---------- ball query: one wave per center, ordered first-32 collection ----------
__global__ __launch_bounds__(256) void ballq_kernel(const float* __restrict__ coords,
                                                    const int* __restrict__ cidx,
                                                    int* __restrict__ nbidx) {
  const int wib = threadIdx.x >> 6;
  const int gw = blockIdx.x * 4 + wib;
  const int lane = threadIdx.x & 63;
  const int b = gw >> 11;
  const float* C = coords + (size_t)b * 3 * NPTS;
  const int ci = cidx[gw];
  const float cx = C[ci], cy = C[NPTS + ci], cz = C[2 * NPTS + ci];
  // python double 0.2*0.2 demoted to f32 == 0x3D23D70A (NOT 0.2f*0.2f!)
  const float R2 = (float)(0.2 * 0.2);
  __shared__ int sbuf[4][32];
  int* buf = sbuf[wib];
  int count = 0;
  for (int base = 0; base < NPTS && count < 32; base += 64) {
    const int i = base + lane;
    float dx = __fsub_rn(cx, C[i]);
    float dy = __fsub_rn(cy, C[NPTS + i]);
    float dz = __fsub_rn(cz, C[2 * NPTS + i]);
    float d2 = __fadd_rn(__fadd_rn(__fmul_rn(dx, dx), __fmul_rn(dy, dy)), __fmul_rn(dz, dz));
    bool q = d2 < R2;
    unsigned long long mk = __ballot(q ? 1 : 0);
    int pos = count + (int)__popcll(mk & ((1ull << lane) - 1ull));
    if (q && pos < 32) buf[pos] = i;
    count += (int)__popcll(mk);
  }
  __syncthreads();
  if (lane < 32) {
    int cnt = count < 32 ? count : 32;
    int first = (count > 0) ? buf[0] : 0;
    int v = (lane < cnt) ? buf[lane] : first;
    nbidx[(size_t)gw * KNB + lane] = v;
  }
}

// ---------- MLP helpers ----------
__device__ __forceinline__ void layer_accum(const float* __restrict__ Wcol,
                                            const float* __restrict__ X, int Cin,
                                            int ldw, float bias, float acc[32]) {
#pragma unroll
  for (int k = 0; k < 32; ++k) acc[k] = bias;
  for (int c = 0; c < Cin; ++c) {
    float w = Wcol[c * ldw];
    const float4* xr = (const float4*)(X + c * 36);
#pragma unroll
    for (int q = 0; q < 8; ++q) {
      float4 xv = xr[q];
      acc[4 * q + 0] = fmaf(w, xv.x, acc[4 * q + 0]);
      acc[4 * q + 1] = fmaf(w, xv.y, acc[4 * q + 1]);
      acc[4 * q + 2] = fmaf(w, xv.z, acc[4 * q + 2]);
      acc[4 * q + 3] = fmaf(w, xv.w, acc[4 * q + 3]);
    }
  }
}

__device__ __forceinline__ void store_relu(float* __restrict__ row, const float acc[32]) {
#pragma unroll
  for (int q = 0; q < 8; ++q) {
    float4 v;
    v.x = fmaxf(acc[4 * q + 0], 0.f);
    v.y = fmaxf(acc[4 * q + 1], 0.f);
    v.z = fmaxf(acc[4 * q + 2], 0.f);
    v.w = fmaxf(acc[4 * q + 3], 0.f);
    *(float4*)(row + 4 * q) = v;
  }
}

// ---------- gather + 3-layer MLP + maxpool: one wave per center ----------
__global__ __launch_bounds__(64) void mlp_kernel(const float* __restrict__ coords,
                                                 const float* __restrict__ featT,
                                                 const float* __restrict__ Wt,
                                                 const float* __restrict__ b1,
                                                 const float* __restrict__ b2,
                                                 const float* __restrict__ b3,
                                                 const int* __restrict__ cidx,
                                                 const int* __restrict__ nbidx,
                                                 float* __restrict__ outT) {
  const int g = blockIdx.x;
  const int b = g >> 11;
  const int lane = threadIdx.x;
  __shared__ __align__(16) float A[64 * 36];
  __shared__ __align__(16) float Bf[64 * 36];
  const float* C = coords + (size_t)b * 3 * NPTS;
  const int ci = cidx[g];
  const float ccx = C[ci], ccy = C[NPTS + ci], ccz = C[2 * NPTS + ci];
  const int* nb = nbidx + (size_t)g * KNB;
  if (lane < 32) {
    const int n = nb[lane];
    A[0 * 36 + lane] = C[n] - ccx;
    A[1 * 36 + lane] = C[NPTS + n] - ccy;
    A[2 * 36 + lane] = C[2 * NPTS + n] - ccz;
    const float4* f = (const float4*)(featT + ((size_t)b * NPTS + n) * 32);
#pragma unroll
    for (int q = 0; q < 4; ++q) {
      float4 v = f[q];
      A[(3 + 4 * q) * 36 + lane] = v.x;
      A[(4 + 4 * q) * 36 + lane] = v.y;
      A[(5 + 4 * q) * 36 + lane] = v.z;
      A[(6 + 4 * q) * 36 + lane] = v.w;
    }
  } else {
    const int k = lane - 32;
    const int n = nb[k];
    const float4* f = (const float4*)(featT + ((size_t)b * NPTS + n) * 32);
#pragma unroll
    for (int q = 4; q < 8; ++q) {
      float4 v = f[q];
      A[(3 + 4 * q) * 36 + k] = v.x;
      A[(4 + 4 * q) * 36 + k] = v.y;
      A[(5 + 4 * q) * 36 + k] = v.z;
      A[(6 + 4 * q) * 36 + k] = v.w;
    }
  }
  __syncthreads();
  float acc[32];
  layer_accum(Wt + lane, A, 35, 64, b1[lane], acc);
  store_relu(&Bf[lane * 36], acc);
  __syncthreads();
  layer_accum(Wt + 2240 + lane, Bf, 64, 64, b2[lane], acc);
  __syncthreads();
  store_relu(&A[lane * 36], acc);
  __syncthreads();
  float* outp = outT + (size_t)g * 128;
#pragma unroll 1
  for (int h = 0; h < 2; ++h) {
    layer_accum(Wt + 6336 + h * 64 + lane, A, 64, 128, b3[h * 64 + lane], acc);
    float mx = 0.f;  // relu then max == max then clamp at 0
#pragma unroll
    for (int k = 0; k < 32; ++k) mx = fmaxf(mx, acc[k]);
    outp[h * 64 + lane] = mx;
  }
}

// ---------- output transpose (B,M,128) -> (B,128,M) ----------
__global__ __launch_bounds__(256) void outT_kernel(const float* __restrict__ outT,
                                                   float* __restrict__ out) {
  const int bid = blockIdx.x;
  const int b = bid >> 8;
  const int r = bid & 255;
  const int o0 = (r >> 6) * 32;
  const int m0 = (r & 63) * 32;
  __shared__ float tile[32][33];
  const int tx = threadIdx.x & 31, ty = threadIdx.x >> 5;
  const float* src = outT + ((size_t)b * MCTR + m0) * 128;
#pragma unroll
  for (int s = 0; s < 4; ++s) {
    int m = ty + 8 * s;
    tile[m][tx] = src[(size_t)m * 128 + o0 + tx];
  }
  __syncthreads();
  float* dst = out + ((size_t)b * 128 + o0) * MCTR + m0;
#pragma unroll
  for (int s = 0; s < 4; ++s) {
    int o = ty + 8 * s;
    dst[(size_t)o * MCTR + tx] = tile[tx][o];
  }
}

extern "C" void kernel_launch(void* const* d_in, const int* in_sizes, int n_in,
                              void* d_out, int out_size, void* d_ws, size_t ws_size,
                              hipStream_t stream) {
  (void)in_sizes; (void)n_in; (void)out_size; (void)ws_size;
  const float* feats = (const float*)d_in[0];
  const float* coords = (const float*)d_in[1];
  const float* W1 = (const float*)d_in[2];
  const float* b1 = (const float*)d_in[3];
  const float* W2 = (const float*)d_in[4];
  const float* b2 = (const float*)d_in[5];
  const float* W3 = (const float*)d_in[6];
  const float* b3 = (const float*)d_in[7];
  float* out = (float*)d_out;
  float* centers = out + (size_t)BATCH * 128 * MCTR;

  float* ws_f = (float*)d_ws;
  float* featT = ws_f;                                     // 1,048,576 f
  float* Wt = ws_f + 1048576;                              //    14,528 f
  int* cidx = (int*)(ws_f + 1048576 + 14528);              //     8,192 i
  int* nbidx = (int*)(ws_f + 1048576 + 14528 + 8192);      //   262,144 i
  float* outTbuf = ws_f + 1048576 + 14528 + 8192 + 262144; // 1,048,576 f
  // sorted-coord arrays overlay outTbuf: dead before mlp_kernel writes it
  float* sX = outTbuf;                     // 32768 f
  float* sY = outTbuf + 32768;             // 32768 f
  float* sZ = outTbuf + 65536;             // 32768 f
  int* sOrig = (int*)(outTbuf + 98304);    // 32768 i
  int* bstartG = (int*)(outTbuf + 131072); // 4*513 i

  featT_kernel<<<1024, 256, 0, stream>>>(feats, featT);
  prep_kernel<<<32, 256, 0, stream>>>(W1, W2, W3, Wt);
  xsort_kernel<<<BATCH, 512, 0, stream>>>(coords, sX, sY, sZ, sOrig, bstartG);
  fps_kernel<<<BATCH, 512, 0, stream>>>(sX, sY, sZ, sOrig, bstartG, cidx, centers);
  ballq_kernel<<<2048, 256, 0, stream>>>(coords, cidx, nbidx);
  mlp_kernel<<<BATCH * MCTR, 64, 0, stream>>>(coords, featT, Wt, b1, b2, b3, cidx, nbidx, outTbuf);
  outT_kernel<<<1024, 256, 0, stream>>>(outTbuf, out);
}

// Round 9
// 2001.552 us; speedup vs baseline: 1.5757x; 1.5757x over previous
//
#include <hip/hip_runtime.h>
#include <cstdint>
#include <cstddef>

#define NPTS 8192
#define MCTR 2048
#define BATCH 4
#define KNB 32

__device__ __forceinline__ unsigned long long u64max(unsigned long long a,
                                                     unsigned long long b) {
  return a > b ? a : b;
}

// ---- u64 wave max via DPP (identity 0), 6 steps, broadcast from lane 63 ----
// row_shr:N moves data toward HIGHER lanes (lane i receives lane i-N).
__device__ __forceinline__ unsigned long long wave_max_key(unsigned long long k) {
#define STEPK(ctrl, rmask, bmask)                                                         \
  {                                                                                       \
    int lo_ = __builtin_amdgcn_update_dpp(0, (int)(unsigned)(k & 0xffffffffull), ctrl,    \
                                          rmask, bmask, false);                           \
    int hi_ = __builtin_amdgcn_update_dpp(0, (int)(unsigned)(k >> 32), ctrl, rmask,       \
                                          bmask, false);                                  \
    unsigned long long o_ =                                                               \
        ((unsigned long long)(unsigned)hi_ << 32) | (unsigned)lo_;                        \
    k = k > o_ ? k : o_;                                                                  \
  }
  STEPK(0x111, 0xf, 0xf)  // row_shr:1
  STEPK(0x112, 0xf, 0xf)  // row_shr:2
  STEPK(0x114, 0xf, 0xf)  // row_shr:4
  STEPK(0x118, 0xf, 0xf)  // row_shr:8
  STEPK(0x142, 0xa, 0xf)  // row_bcast:15
  STEPK(0x143, 0xc, 0xf)  // row_bcast:31
#undef STEPK
  int lo = __builtin_amdgcn_readlane((int)(unsigned)(k & 0xffffffffull), 63);
  int hi = __builtin_amdgcn_readlane((int)(unsigned)(k >> 32), 63);
  return ((unsigned long long)(unsigned)hi << 32) | (unsigned)lo;
}

// ---- u64 max over lanes 0..7 -> accumulates in lane SEVEN (row_shr pushes
// data to higher lanes: l7=max(7,3) -> max(7,3,5,1) -> max(all 8)); broadcast
// via readlane(7). R8 BUG: readlane(0) read an untouched lane. ----
__device__ __forceinline__ unsigned long long oct_max_key(unsigned long long k) {
#define STEPK(ctrl)                                                                       \
  {                                                                                       \
    int lo_ = __builtin_amdgcn_update_dpp(0, (int)(unsigned)(k & 0xffffffffull), ctrl,    \
                                          0xf, 0xf, false);                               \
    int hi_ = __builtin_amdgcn_update_dpp(0, (int)(unsigned)(k >> 32), ctrl, 0xf, 0xf,    \
                                          false);                                         \
    unsigned long long o_ =                                                               \
        ((unsigned long long)(unsigned)hi_ << 32) | (unsigned)lo_;                        \
    k = k > o_ ? k : o_;                                                                  \
  }
  STEPK(0x114)  // row_shr:4 -> lane7 = max(l7,l3); lane6 = max(l6,l2); ...
  STEPK(0x112)  // row_shr:2 -> lane7 = max(l7,l3,l5,l1); lane6 = max(l6,l2,l4,l0)
  STEPK(0x111)  // row_shr:1 -> lane7 = max over lanes 0..7
#undef STEPK
  int lo = __builtin_amdgcn_readlane((int)(unsigned)(k & 0xffffffffull), 7);
  int hi = __builtin_amdgcn_readlane((int)(unsigned)(k >> 32), 7);
  return ((unsigned long long)(unsigned)hi << 32) | (unsigned)lo;
}

// ---------- feature transpose (B,32,N) -> (B,N,32) ----------
__global__ __launch_bounds__(256) void featT_kernel(const float* __restrict__ feats,
                                                    float* __restrict__ featT) {
  const int bn = blockIdx.x;
  const int b = bn >> 8;
  const int n0 = (bn & 255) * 32;
  __shared__ float tile[32][33];
  const int tx = threadIdx.x & 31, ty = threadIdx.x >> 5;
  const float* src = feats + (size_t)b * 32 * NPTS;
#pragma unroll
  for (int s = 0; s < 4; ++s) {
    int f = ty + 8 * s;
    tile[f][tx] = src[(size_t)f * NPTS + n0 + tx];
  }
  __syncthreads();
  float* dst = featT + ((size_t)b * NPTS + n0) * 32;
#pragma unroll
  for (int s = 0; s < 4; ++s) {
    int n = ty + 8 * s;
    dst[n * 32 + tx] = tile[tx][n];
  }
}

// ---------- weight transpose ----------
__global__ __launch_bounds__(256) void prep_kernel(const float* __restrict__ W1,
                                                   const float* __restrict__ W2,
                                                   const float* __restrict__ W3,
                                                   float* __restrict__ Wt) {
  const int t = blockIdx.x * 256 + threadIdx.x;
  if (t < 2240) { int c = t >> 6, o = t & 63;  Wt[t] = W1[o * 35 + c]; }
  if (t < 4096) { int c = t >> 6, o = t & 63;  Wt[2240 + t] = W2[o * 64 + c]; }
  if (t < 8192) { int c = t >> 7, o = t & 127; Wt[6336 + t] = W3[o * 64 + c]; }
}

// ---------- counting sort by x-bucket (512 buckets), one block per batch ----------
// Within-bucket order is nondeterministic (atomic cursors) — harmless: all
// downstream selection is keyed on (distance, ORIGINAL index), never slot order.
__global__ __launch_bounds__(512) void xsort_kernel(const float* __restrict__ coords,
                                                    float* __restrict__ sX,
                                                    float* __restrict__ sY,
                                                    float* __restrict__ sZ,
                                                    int* __restrict__ sOrig) {
  const int b = blockIdx.x;
  const int tid = threadIdx.x;
  const float* C = coords + (size_t)b * 3 * NPTS;
  __shared__ int h[512];
  __shared__ int cur[512];
  h[tid] = 0;
  __syncthreads();
  int bk[16];
#pragma unroll
  for (int j = 0; j < 16; ++j) {
    int i = tid + j * 512;
    float x = C[i];
    int k = (int)(x * 512.0f);
    k = k < 0 ? 0 : (k > 511 ? 511 : k);
    bk[j] = k;
    atomicAdd(&h[k], 1);
  }
  __syncthreads();
  const int cnt = h[tid];
  for (int s = 1; s < 512; s <<= 1) {  // Hillis-Steele inclusive scan
    int v = (tid >= s) ? h[tid - s] : 0;
    __syncthreads();
    h[tid] += v;
    __syncthreads();
  }
  cur[tid] = h[tid] - cnt;  // exclusive start of bucket tid
  __syncthreads();
  float* dX = sX + (size_t)b * NPTS;
  float* dY = sY + (size_t)b * NPTS;
  float* dZ = sZ + (size_t)b * NPTS;
  int* dO = sOrig + (size_t)b * NPTS;
#pragma unroll
  for (int j = 0; j < 16; ++j) {
    int i = tid + j * 512;
    int pos = atomicAdd(&cur[bk[j]], 1);
    dX[pos] = C[i];
    dY[pos] = C[NPTS + i];
    dZ[pos] = C[2 * NPTS + i];
    dO[pos] = i;
  }
}

// ---------- furthest point sampling: blocked ownership + exact bbox culling ----------
// Thread t owns x-sorted slots [16t,16t+16) (registers). Coords in LDS as float4
// (centroid fetch = ONE ds_read_b128). Cross-wave reduce = lane-parallel: each wave
// reads skey[lane&7] (one ds_read_b64, multicast) + 3-step DPP u64 max — the
// post-barrier chain is 2 LDS ops/wave instead of 7. No global ops in the loop.
// Skip rule (exact): lb*(1-1e-6) >= cmax -> no dd in block can change (margin >>
// 8 ulp of the reference d2 chain). Key = (distbits<<32)|((8191-orig)<<13)|slot
// -> u64 max == (max dist, min ORIGINAL idx) == jnp.argmax first occurrence.
__global__ __launch_bounds__(512) void fps_kernel(const float* __restrict__ sX,
                                                  const float* __restrict__ sY,
                                                  const float* __restrict__ sZ,
                                                  const int* __restrict__ sOrig,
                                                  int* __restrict__ cidx,
                                                  float* __restrict__ centers) {
  const int b = blockIdx.x;
  const int tid = threadIdx.x;
  const int wave = tid >> 6, lane = tid & 63;
  __shared__ __align__(16) float4 lC4[NPTS];  // 128 KiB
  __shared__ __align__(16) unsigned long long skey[2][8];
  __shared__ int s_slot0;
  const float* gX = sX + (size_t)b * NPTS;
  const float* gY = sY + (size_t)b * NPTS;
  const float* gZ = sZ + (size_t)b * NPTS;
  const int* gO = sOrig + (size_t)b * NPTS;
  for (int i = tid; i < NPTS; i += 512) {
    float4 v;
    v.x = gX[i]; v.y = gY[i]; v.z = gZ[i]; v.w = 0.0f;
    lC4[i] = v;
  }
  const int base = tid * 16;
  int og[16];
#pragma unroll
  for (int j = 0; j < 16; ++j) {
    og[j] = gO[base + j];
    if (og[j] == 0) s_slot0 = base + j;  // exactly one thread writes
  }
  __syncthreads();
  float px[16], py[16], pz[16], dd[16];
#pragma unroll
  for (int j = 0; j < 16; ++j) {
    float4 c = lC4[base + j];
    px[j] = c.x; py[j] = c.y; pz[j] = c.z;
    dd[j] = __builtin_inff();
  }
  // exact bbox of owned points
  float xlo = px[0], xhi = px[0], ylo = py[0], yhi = py[0], zlo = pz[0], zhi = pz[0];
#pragma unroll
  for (int j = 1; j < 16; ++j) {
    xlo = fminf(xlo, px[j]); xhi = fmaxf(xhi, px[j]);
    ylo = fminf(ylo, py[j]); yhi = fmaxf(yhi, py[j]);
    zlo = fminf(zlo, pz[j]); zhi = fmaxf(zhi, pz[j]);
  }
  float cmax = __builtin_inff();
  int amin17 = (og[0] << 4) | 0;
#pragma unroll
  for (int j = 1; j < 16; ++j) amin17 = min(amin17, (og[j] << 4) | j);
  const int slot0 = s_slot0;
  float4 cc = lC4[slot0];
  float cx = cc.x, cy = cc.y, cz = cc.z;
  unsigned long long wkey = 0;
  unsigned long long kreg[4];
  if (tid == 0)  // m=0: initial point, orig 0 (dist bits unused by writeback)
    kreg[0] = ((unsigned long long)(unsigned)8191 << 13) | (unsigned)slot0;
  int buf = 0;
  for (int it = 0; it < MCTR; ++it) {
    // lower bound on dist^2(centroid, any owned point)
    float dxm = fmaxf(fmaxf(xlo - cx, cx - xhi), 0.0f);
    float dym = fmaxf(fmaxf(ylo - cy, cy - yhi), 0.0f);
    float dzm = fmaxf(fmaxf(zlo - cz, cz - zhi), 0.0f);
    float lb = dxm * dxm + dym * dym + dzm * dzm;
    bool active = !(lb * 0.999999f >= cmax);  // margin makes skip provably exact
    unsigned long long mk = __ballot(active ? 1 : 0);
    if (mk != 0ull) {
      if (active) {
#pragma unroll
        for (int j = 0; j < 16; ++j) {
          // EXACT reference order: (dx*dx + dy*dy) + dz*dz, rn each step, no FMA
          float dx = __fsub_rn(px[j], cx);
          float dy = __fsub_rn(py[j], cy);
          float dz = __fsub_rn(pz[j], cz);
          float d = __fadd_rn(__fadd_rn(__fmul_rn(dx, dx), __fmul_rn(dy, dy)),
                              __fmul_rn(dz, dz));
          dd[j] = fminf(dd[j], d);
        }
        float a0 = fmaxf(fmaxf(dd[0], dd[1]), dd[2]);
        float a1 = fmaxf(fmaxf(dd[3], dd[4]), dd[5]);
        float a2 = fmaxf(fmaxf(dd[6], dd[7]), dd[8]);
        float a3 = fmaxf(fmaxf(dd[9], dd[10]), dd[11]);
        float a4 = fmaxf(fmaxf(dd[12], dd[13]), dd[14]);
        cmax = fmaxf(fmaxf(fmaxf(a0, a1), a2), fmaxf(fmaxf(a3, a4), dd[15]));
        amin17 = 0x7fffffff;  // min ORIGINAL idx among achievers of cmax
#pragma unroll
        for (int j = 0; j < 16; ++j)
          amin17 = min(amin17, (dd[j] == cmax) ? ((og[j] << 4) | j) : 0x7fffffff);
      }
      unsigned long long key =
          ((unsigned long long)__float_as_uint(cmax) << 32) |
          ((unsigned long long)(unsigned)(8191 - (amin17 >> 4)) << 13) |
          (unsigned long long)(unsigned)(base + (amin17 & 15));
      wkey = wave_max_key(key);
      if (lane == 0) skey[buf][wave] = wkey;
    } else {
      if (lane == 0) skey[buf][wave] = wkey;  // nothing changed in this wave
    }
    __syncthreads();
    // cross-wave reduce, lane-parallel: 1 multicast b64 read + 3-step DPP max
    unsigned long long gk = oct_max_key(skey[buf][lane & 7]);
    if (((it + 1) >> 2) == tid) kreg[(it + 1) & 3] = gk;  // winner for m=it+1
    const int slot = (int)(gk & 0x1fff);
    float4 c2 = lC4[slot];  // ONE ds_read_b128, wave-uniform
    cx = c2.x; cy = c2.y; cz = c2.z;
    buf ^= 1;
  }
  // coalesced writeback: thread t owns centers m = 4t..4t+3
#pragma unroll
  for (int r = 0; r < 4; ++r) {
    unsigned long long k = kreg[r];
    int orig = 8191 - (int)((k >> 13) & 0x1fff);
    int sl = (int)(k & 0x1fff);
    int m = 4 * tid + r;
    float4 c = lC4[sl];
    cidx[b * MCTR + m] = orig;
    centers[(size_t)b * 3 * MCTR + m] = c.x;
    centers[(size_t)b * 3 * MCTR + MCTR + m] = c.y;
    centers[(size_t)b * 3 * MCTR + 2 * MCTR + m] = c.z;
  }
}

// ---------- ball query: one wave per center, ordered first-32 collection ----------
__global__ __launch_bounds__(256) void ballq_kernel(const float* __restrict__ coords,
                                                    const int* __restrict__ cidx,
                                                    int* __restrict__ nbidx) {
  const int wib = threadIdx.x >> 6;
  const int gw = blockIdx.x * 4 + wib;
  const int lane = threadIdx.x & 63;
  const int b = gw >> 11;
  const float* C = coords + (size_t)b * 3 * NPTS;
  const int ci = cidx[gw];
  const float cx = C[ci], cy = C[NPTS + ci], cz = C[2 * NPTS + ci];
  // python double 0.2*0.2 demoted to f32 == 0x3D23D70A (NOT 0.2f*0.2f!)
  const float R2 = (float)(0.2 * 0.2);
  __shared__ int sbuf[4][32];
  int* buf = sbuf[wib];
  int count = 0;
  for (int base = 0; base < NPTS && count < 32; base += 64) {
    const int i = base + lane;
    float dx = __fsub_rn(cx, C[i]);
    float dy = __fsub_rn(cy, C[NPTS + i]);
    float dz = __fsub_rn(cz, C[2 * NPTS + i]);
    float d2 = __fadd_rn(__fadd_rn(__fmul_rn(dx, dx), __fmul_rn(dy, dy)), __fmul_rn(dz, dz));
    bool q = d2 < R2;
    unsigned long long mk = __ballot(q ? 1 : 0);
    int pos = count + (int)__popcll(mk & ((1ull << lane) - 1ull));
    if (q && pos < 32) buf[pos] = i;
    count += (int)__popcll(mk);
  }
  __syncthreads();
  if (lane < 32) {
    int cnt = count < 32 ? count : 32;
    int first = (count > 0) ? buf[0] : 0;
    int v = (lane < cnt) ? buf[lane] : first;
    nbidx[(size_t)gw * KNB + lane] = v;
  }
}

// ---------- MLP helpers ----------
__device__ __forceinline__ void layer_accum(const float* __restrict__ Wcol,
                                            const float* __restrict__ X, int Cin,
                                            int ldw, float bias, float acc[32]) {
#pragma unroll
  for (int k = 0; k < 32; ++k) acc[k] = bias;
  for (int c = 0; c < Cin; ++c) {
    float w = Wcol[c * ldw];
    const float4* xr = (const float4*)(X + c * 36);
#pragma unroll
    for (int q = 0; q < 8; ++q) {
      float4 xv = xr[q];
      acc[4 * q + 0] = fmaf(w, xv.x, acc[4 * q + 0]);
      acc[4 * q + 1] = fmaf(w, xv.y, acc[4 * q + 1]);
      acc[4 * q + 2] = fmaf(w, xv.z, acc[4 * q + 2]);
      acc[4 * q + 3] = fmaf(w, xv.w, acc[4 * q + 3]);
    }
  }
}

__device__ __forceinline__ void store_relu(float* __restrict__ row, const float acc[32]) {
#pragma unroll
  for (int q = 0; q < 8; ++q) {
    float4 v;
    v.x = fmaxf(acc[4 * q + 0], 0.f);
    v.y = fmaxf(acc[4 * q + 1], 0.f);
    v.z = fmaxf(acc[4 * q + 2], 0.f);
    v.w = fmaxf(acc[4 * q + 3], 0.f);
    *(float4*)(row + 4 * q) = v;
  }
}

// ---------- gather + 3-layer MLP + maxpool: one wave per center ----------
__global__ __launch_bounds__(64) void mlp_kernel(const float* __restrict__ coords,
                                                 const float* __restrict__ featT,
                                                 const float* __restrict__ Wt,
                                                 const float* __restrict__ b1,
                                                 const float* __restrict__ b2,
                                                 const float* __restrict__ b3,
                                                 const int* __restrict__ cidx,
                                                 const int* __restrict__ nbidx,
                                                 float* __restrict__ outT) {
  const int g = blockIdx.x;
  const int b = g >> 11;
  const int lane = threadIdx.x;
  __shared__ __align__(16) float A[64 * 36];
  __shared__ __align__(16) float Bf[64 * 36];
  const float* C = coords + (size_t)b * 3 * NPTS;
  const int ci = cidx[g];
  const float ccx = C[ci], ccy = C[NPTS + ci], ccz = C[2 * NPTS + ci];
  const int* nb = nbidx + (size_t)g * KNB;
  if (lane < 32) {
    const int n = nb[lane];
    A[0 * 36 + lane] = C[n] - ccx;
    A[1 * 36 + lane] = C[NPTS + n] - ccy;
    A[2 * 36 + lane] = C[2 * NPTS + n] - ccz;
    const float4* f = (const float4*)(featT + ((size_t)b * NPTS + n) * 32);
#pragma unroll
    for (int q = 0; q < 4; ++q) {
      float4 v = f[q];
      A[(3 + 4 * q) * 36 + lane] = v.x;
      A[(4 + 4 * q) * 36 + lane] = v.y;
      A[(5 + 4 * q) * 36 + lane] = v.z;
      A[(6 + 4 * q) * 36 + lane] = v.w;
    }
  } else {
    const int k = lane - 32;
    const int n = nb[k];
    const float4* f = (const float4*)(featT + ((size_t)b * NPTS + n) * 32);
#pragma unroll
    for (int q = 4; q < 8; ++q) {
      float4 v = f[q];
      A[(3 + 4 * q) * 36 + k] = v.x;
      A[(4 + 4 * q) * 36 + k] = v.y;
      A[(5 + 4 * q) * 36 + k] = v.z;
      A[(6 + 4 * q) * 36 + k] = v.w;
    }
  }
  __syncthreads();
  float acc[32];
  layer_accum(Wt + lane, A, 35, 64, b1[lane], acc);
  store_relu(&Bf[lane * 36], acc);
  __syncthreads();
  layer_accum(Wt + 2240 + lane, Bf, 64, 64, b2[lane], acc);
  __syncthreads();
  store_relu(&A[lane * 36], acc);
  __syncthreads();
  float* outp = outT + (size_t)g * 128;
#pragma unroll 1
  for (int h = 0; h < 2; ++h) {
    layer_accum(Wt + 6336 + h * 64 + lane, A, 64, 128, b3[h * 64 + lane], acc);
    float mx = 0.f;  // relu then max == max then clamp at 0
#pragma unroll
    for (int k = 0; k < 32; ++k) mx = fmaxf(mx, acc[k]);
    outp[h * 64 + lane] = mx;
  }
}

// ---------- output transpose (B,M,128) -> (B,128,M) ----------
__global__ __launch_bounds__(256) void outT_kernel(const float* __restrict__ outT,
                                                   float* __restrict__ out) {
  const int bid = blockIdx.x;
  const int b = bid >> 8;
  const int r = bid & 255;
  const int o0 = (r >> 6) * 32;
  const int m0 = (r & 63) * 32;
  __shared__ float tile[32][33];
  const int tx = threadIdx.x & 31, ty = threadIdx.x >> 5;
  const float* src = outT + ((size_t)b * MCTR + m0) * 128;
#pragma unroll
  for (int s = 0; s < 4; ++s) {
    int m = ty + 8 * s;
    tile[m][tx] = src[(size_t)m * 128 + o0 + tx];
  }
  __syncthreads();
  float* dst = out + ((size_t)b * 128 + o0) * MCTR + m0;
#pragma unroll
  for (int s = 0; s < 4; ++s) {
    int o = ty + 8 * s;
    dst[(size_t)o * MCTR + tx] = tile[tx][o];
  }
}

extern "C" void kernel_launch(void* const* d_in, const int* in_sizes, int n_in,
                              void* d_out, int out_size, void* d_ws, size_t ws_size,
                              hipStream_t stream) {
  (void)in_sizes; (void)n_in; (void)out_size; (void)ws_size;
  const float* feats = (const float*)d_in[0];
  const float* coords = (const float*)d_in[1];
  const float* W1 = (const float*)d_in[2];
  const float* b1 = (const float*)d_in[3];
  const float* W2 = (const float*)d_in[4];
  const float* b2 = (const float*)d_in[5];
  const float* W3 = (const float*)d_in[6];
  const float* b3 = (const float*)d_in[7];
  float* out = (float*)d_out;
  float* centers = out + (size_t)BATCH * 128 * MCTR;

  float* ws_f = (float*)d_ws;
  float* featT = ws_f;                                     // 1,048,576 f
  float* Wt = ws_f + 1048576;                              //    14,528 f
  int* cidx = (int*)(ws_f + 1048576 + 14528);              //     8,192 i
  int* nbidx = (int*)(ws_f + 1048576 + 14528 + 8192);      //   262,144 i
  float* outTbuf = ws_f + 1048576 + 14528 + 8192 + 262144; // 1,048,576 f
  // sorted-coord arrays overlay outTbuf: dead before mlp_kernel writes it
  float* sX = outTbuf;                 // 32768 f
  float* sY = outTbuf + 32768;         // 32768 f
  float* sZ = outTbuf + 65536;         // 32768 f
  int* sOrig = (int*)(outTbuf + 98304);// 32768 i

  featT_kernel<<<1024, 256, 0, stream>>>(feats, featT);
  prep_kernel<<<32, 256, 0, stream>>>(W1, W2, W3, Wt);
  xsort_kernel<<<BATCH, 512, 0, stream>>>(coords, sX, sY, sZ, sOrig);
  fps_kernel<<<BATCH, 512, 0, stream>>>(sX, sY, sZ, sOrig, cidx, centers);
  ballq_kernel<<<2048, 256, 0, stream>>>(coords, cidx, nbidx);
  mlp_kernel<<<BATCH * MCTR, 64, 0, stream>>>(coords, featT, Wt, b1, b2, b3, cidx, nbidx, outTbuf);
  outT_kernel<<<1024, 256, 0, stream>>>(outTbuf, out);
}

// Round 10
// 1976.756 us; speedup vs baseline: 1.5954x; 1.0125x over previous
//
#include <hip/hip_runtime.h>
#include <cstdint>
#include <cstddef>

#define NPTS 8192
#define MCTR 2048
#define BATCH 4
#define KNB 32

__device__ __forceinline__ unsigned long long u64max(unsigned long long a,
                                                     unsigned long long b) {
  return a > b ? a : b;
}

// ---- u64 wave max via DPP (identity 0), 6 steps, broadcast from lane 63 ----
// row_shr:N moves data toward HIGHER lanes (lane i receives lane i-N).
__device__ __forceinline__ unsigned long long wave_max_key(unsigned long long k) {
#define STEPK(ctrl, rmask, bmask)                                                         \
  {                                                                                       \
    int lo_ = __builtin_amdgcn_update_dpp(0, (int)(unsigned)(k & 0xffffffffull), ctrl,    \
                                          rmask, bmask, false);                           \
    int hi_ = __builtin_amdgcn_update_dpp(0, (int)(unsigned)(k >> 32), ctrl, rmask,       \
                                          bmask, false);                                  \
    unsigned long long o_ =                                                               \
        ((unsigned long long)(unsigned)hi_ << 32) | (unsigned)lo_;                        \
    k = k > o_ ? k : o_;                                                                  \
  }
  STEPK(0x111, 0xf, 0xf)  // row_shr:1
  STEPK(0x112, 0xf, 0xf)  // row_shr:2
  STEPK(0x114, 0xf, 0xf)  // row_shr:4
  STEPK(0x118, 0xf, 0xf)  // row_shr:8
  STEPK(0x142, 0xa, 0xf)  // row_bcast:15
  STEPK(0x143, 0xc, 0xf)  // row_bcast:31
#undef STEPK
  int lo = __builtin_amdgcn_readlane((int)(unsigned)(k & 0xffffffffull), 63);
  int hi = __builtin_amdgcn_readlane((int)(unsigned)(k >> 32), 63);
  return ((unsigned long long)(unsigned)hi << 32) | (unsigned)lo;
}

// ---- u64 max over lanes 0..7 -> accumulates in lane SEVEN (row_shr pushes
// data to higher lanes); broadcast via readlane(7). ----
__device__ __forceinline__ unsigned long long oct_max_key(unsigned long long k) {
#define STEPK(ctrl)                                                                       \
  {                                                                                       \
    int lo_ = __builtin_amdgcn_update_dpp(0, (int)(unsigned)(k & 0xffffffffull), ctrl,    \
                                          0xf, 0xf, false);                               \
    int hi_ = __builtin_amdgcn_update_dpp(0, (int)(unsigned)(k >> 32), ctrl, 0xf, 0xf,    \
                                          false);                                         \
    unsigned long long o_ =                                                               \
        ((unsigned long long)(unsigned)hi_ << 32) | (unsigned)lo_;                        \
    k = k > o_ ? k : o_;                                                                  \
  }
  STEPK(0x114)  // row_shr:4
  STEPK(0x112)  // row_shr:2
  STEPK(0x111)  // row_shr:1 -> lane7 = max over lanes 0..7
#undef STEPK
  int lo = __builtin_amdgcn_readlane((int)(unsigned)(k & 0xffffffffull), 7);
  int hi = __builtin_amdgcn_readlane((int)(unsigned)(k >> 32), 7);
  return ((unsigned long long)(unsigned)hi << 32) | (unsigned)lo;
}

// ---------- feature transpose (B,32,N) -> (B,N,32) ----------
__global__ __launch_bounds__(256) void featT_kernel(const float* __restrict__ feats,
                                                    float* __restrict__ featT) {
  const int bn = blockIdx.x;
  const int b = bn >> 8;
  const int n0 = (bn & 255) * 32;
  __shared__ float tile[32][33];
  const int tx = threadIdx.x & 31, ty = threadIdx.x >> 5;
  const float* src = feats + (size_t)b * 32 * NPTS;
#pragma unroll
  for (int s = 0; s < 4; ++s) {
    int f = ty + 8 * s;
    tile[f][tx] = src[(size_t)f * NPTS + n0 + tx];
  }
  __syncthreads();
  float* dst = featT + ((size_t)b * NPTS + n0) * 32;
#pragma unroll
  for (int s = 0; s < 4; ++s) {
    int n = ty + 8 * s;
    dst[n * 32 + tx] = tile[tx][n];
  }
}

// ---------- weight transpose ----------
__global__ __launch_bounds__(256) void prep_kernel(const float* __restrict__ W1,
                                                   const float* __restrict__ W2,
                                                   const float* __restrict__ W3,
                                                   float* __restrict__ Wt) {
  const int t = blockIdx.x * 256 + threadIdx.x;
  if (t < 2240) { int c = t >> 6, o = t & 63;  Wt[t] = W1[o * 35 + c]; }
  if (t < 4096) { int c = t >> 6, o = t & 63;  Wt[2240 + t] = W2[o * 64 + c]; }
  if (t < 8192) { int c = t >> 7, o = t & 127; Wt[6336 + t] = W3[o * 64 + c]; }
}

// ---------- counting sort by x-bucket (512 buckets), one block per batch ----------
__global__ __launch_bounds__(512) void xsort_kernel(const float* __restrict__ coords,
                                                    float* __restrict__ sX,
                                                    float* __restrict__ sY,
                                                    float* __restrict__ sZ,
                                                    int* __restrict__ sOrig) {
  const int b = blockIdx.x;
  const int tid = threadIdx.x;
  const float* C = coords + (size_t)b * 3 * NPTS;
  __shared__ int h[512];
  __shared__ int cur[512];
  h[tid] = 0;
  __syncthreads();
  int bk[16];
#pragma unroll
  for (int j = 0; j < 16; ++j) {
    int i = tid + j * 512;
    float x = C[i];
    int k = (int)(x * 512.0f);
    k = k < 0 ? 0 : (k > 511 ? 511 : k);
    bk[j] = k;
    atomicAdd(&h[k], 1);
  }
  __syncthreads();
  const int cnt = h[tid];
  for (int s = 1; s < 512; s <<= 1) {
    int v = (tid >= s) ? h[tid - s] : 0;
    __syncthreads();
    h[tid] += v;
    __syncthreads();
  }
  cur[tid] = h[tid] - cnt;
  __syncthreads();
  float* dX = sX + (size_t)b * NPTS;
  float* dY = sY + (size_t)b * NPTS;
  float* dZ = sZ + (size_t)b * NPTS;
  int* dO = sOrig + (size_t)b * NPTS;
#pragma unroll
  for (int j = 0; j < 16; ++j) {
    int i = tid + j * 512;
    int pos = atomicAdd(&cur[bk[j]], 1);
    dX[pos] = C[i];
    dY[pos] = C[NPTS + i];
    dZ[pos] = C[2 * NPTS + i];
    dO[pos] = i;
  }
}

// ---------- furthest point sampling: blocked ownership + exact bbox culling ----------
// Post-barrier: candidate centroid gather lC4[skey[lane&7]] issued IN PARALLEL with
// the key read; after the oct DPP reduce the winner wave w' = slot>>10 (blocked
// ownership => slot>>4 = tid, >>6 more = wave) and the centroid is recovered with
// 3x readlane(w') — removes one dependent ~120-cyc LDS latency per iteration.
__global__ __launch_bounds__(512) void fps_kernel(const float* __restrict__ sX,
                                                  const float* __restrict__ sY,
                                                  const float* __restrict__ sZ,
                                                  const int* __restrict__ sOrig,
                                                  int* __restrict__ cidx,
                                                  float* __restrict__ centers) {
  const int b = blockIdx.x;
  const int tid = threadIdx.x;
  const int wave = tid >> 6, lane = tid & 63;
  __shared__ __align__(16) float4 lC4[NPTS];  // 128 KiB
  __shared__ __align__(16) unsigned long long skey[2][8];
  __shared__ int s_slot0;
  const float* gX = sX + (size_t)b * NPTS;
  const float* gY = sY + (size_t)b * NPTS;
  const float* gZ = sZ + (size_t)b * NPTS;
  const int* gO = sOrig + (size_t)b * NPTS;
  for (int i = tid; i < NPTS; i += 512) {
    float4 v;
    v.x = gX[i]; v.y = gY[i]; v.z = gZ[i]; v.w = 0.0f;
    lC4[i] = v;
  }
  const int base = tid * 16;
  int og[16];
#pragma unroll
  for (int j = 0; j < 16; ++j) {
    og[j] = gO[base + j];
    if (og[j] == 0) s_slot0 = base + j;  // exactly one thread writes
  }
  __syncthreads();
  float px[16], py[16], pz[16], dd[16];
#pragma unroll
  for (int j = 0; j < 16; ++j) {
    float4 c = lC4[base + j];
    px[j] = c.x; py[j] = c.y; pz[j] = c.z;
    dd[j] = __builtin_inff();
  }
  // exact bbox of owned points
  float xlo = px[0], xhi = px[0], ylo = py[0], yhi = py[0], zlo = pz[0], zhi = pz[0];
#pragma unroll
  for (int j = 1; j < 16; ++j) {
    xlo = fminf(xlo, px[j]); xhi = fmaxf(xhi, px[j]);
    ylo = fminf(ylo, py[j]); yhi = fmaxf(yhi, py[j]);
    zlo = fminf(zlo, pz[j]); zhi = fmaxf(zhi, pz[j]);
  }
  float cmax = __builtin_inff();
  int amin17 = (og[0] << 4) | 0;
#pragma unroll
  for (int j = 1; j < 16; ++j) amin17 = min(amin17, (og[j] << 4) | j);
  const int slot0 = s_slot0;
  float4 cc = lC4[slot0];
  float cx = cc.x, cy = cc.y, cz = cc.z;
  unsigned long long wkey = 0;
  unsigned long long kreg[4];
  if (tid == 0)  // m=0: initial point, orig 0 (dist bits unused by writeback)
    kreg[0] = ((unsigned long long)(unsigned)8191 << 13) | (unsigned)slot0;
  int buf = 0;
  for (int it = 0; it < MCTR; ++it) {
    float dxm = fmaxf(fmaxf(xlo - cx, cx - xhi), 0.0f);
    float dym = fmaxf(fmaxf(ylo - cy, cy - yhi), 0.0f);
    float dzm = fmaxf(fmaxf(zlo - cz, cz - zhi), 0.0f);
    float lb = dxm * dxm + dym * dym + dzm * dzm;
    bool active = !(lb * 0.999999f >= cmax);  // margin makes skip provably exact
    unsigned long long mk = __ballot(active ? 1 : 0);
    if (mk != 0ull) {
      if (active) {
#pragma unroll
        for (int j = 0; j < 16; ++j) {
          // EXACT reference order: (dx*dx + dy*dy) + dz*dz, rn each step, no FMA
          float dx = __fsub_rn(px[j], cx);
          float dy = __fsub_rn(py[j], cy);
          float dz = __fsub_rn(pz[j], cz);
          float d = __fadd_rn(__fadd_rn(__fmul_rn(dx, dx), __fmul_rn(dy, dy)),
                              __fmul_rn(dz, dz));
          dd[j] = fminf(dd[j], d);
        }
        float a0 = fmaxf(fmaxf(dd[0], dd[1]), dd[2]);
        float a1 = fmaxf(fmaxf(dd[3], dd[4]), dd[5]);
        float a2 = fmaxf(fmaxf(dd[6], dd[7]), dd[8]);
        float a3 = fmaxf(fmaxf(dd[9], dd[10]), dd[11]);
        float a4 = fmaxf(fmaxf(dd[12], dd[13]), dd[14]);
        cmax = fmaxf(fmaxf(fmaxf(a0, a1), a2), fmaxf(fmaxf(a3, a4), dd[15]));
        amin17 = 0x7fffffff;
#pragma unroll
        for (int j = 0; j < 16; ++j)
          amin17 = min(amin17, (dd[j] == cmax) ? ((og[j] << 4) | j) : 0x7fffffff);
      }
      unsigned long long key =
          ((unsigned long long)__float_as_uint(cmax) << 32) |
          ((unsigned long long)(unsigned)(8191 - (amin17 >> 4)) << 13) |
          (unsigned long long)(unsigned)(base + (amin17 & 15));
      wkey = wave_max_key(key);
      if (lane == 0) skey[buf][wave] = wkey;
    } else {
      if (lane == 0) skey[buf][wave] = wkey;  // nothing changed in this wave
    }
    __syncthreads();
    // parallel: key read + candidate-centroid gather (both in flight together)
    unsigned long long kc = skey[buf][lane & 7];
    float4 cand = lC4[(int)(kc & 0x1fff)];
    unsigned long long gk = oct_max_key(kc);
    if (((it + 1) >> 2) == tid) kreg[(it + 1) & 3] = gk;  // winner for m=it+1
    const int wwin = (int)((gk & 0x1fff) >> 10);  // winning wave (slot>>4=tid,>>6=wave)
    cx = __int_as_float(__builtin_amdgcn_readlane(__float_as_int(cand.x), wwin));
    cy = __int_as_float(__builtin_amdgcn_readlane(__float_as_int(cand.y), wwin));
    cz = __int_as_float(__builtin_amdgcn_readlane(__float_as_int(cand.z), wwin));
    buf ^= 1;
  }
  // coalesced writeback: thread t owns centers m = 4t..4t+3
#pragma unroll
  for (int r = 0; r < 4; ++r) {
    unsigned long long k = kreg[r];
    int orig = 8191 - (int)((k >> 13) & 0x1fff);
    int sl = (int)(k & 0x1fff);
    int m = 4 * tid + r;
    float4 c = lC4[sl];
    cidx[b * MCTR + m] = orig;
    centers[(size_t)b * 3 * MCTR + m] = c.x;
    centers[(size_t)b * 3 * MCTR + MCTR + m] = c.y;
    centers[(size_t)b * 3 * MCTR + 2 * MCTR + m] = c.z;
  }
}

// ---------- ball query: one wave per center, ordered first-32 collection ----------
__global__ __launch_bounds__(256) void ballq_kernel(const float* __restrict__ coords,
                                                    const int* __restrict__ cidx,
                                                    int* __restrict__ nbidx) {
  const int wib = threadIdx.x >> 6;
  const int gw = blockIdx.x * 4 + wib;
  const int lane = threadIdx.x & 63;
  const int b = gw >> 11;
  const float* C = coords + (size_t)b * 3 * NPTS;
  const int ci = cidx[gw];
  const float cx = C[ci], cy = C[NPTS + ci], cz = C[2 * NPTS + ci];
  // python double 0.2*0.2 demoted to f32 == 0x3D23D70A (NOT 0.2f*0.2f!)
  const float R2 = (float)(0.2 * 0.2);
  __shared__ int sbuf[4][32];
  int* buf = sbuf[wib];
  int count = 0;
  for (int base = 0; base < NPTS && count < 32; base += 64) {
    const int i = base + lane;
    float dx = __fsub_rn(cx, C[i]);
    float dy = __fsub_rn(cy, C[NPTS + i]);
    float dz = __fsub_rn(cz, C[2 * NPTS + i]);
    float d2 = __fadd_rn(__fadd_rn(__fmul_rn(dx, dx), __fmul_rn(dy, dy)), __fmul_rn(dz, dz));
    bool q = d2 < R2;
    unsigned long long mk = __ballot(q ? 1 : 0);
    int pos = count + (int)__popcll(mk & ((1ull << lane) - 1ull));
    if (q && pos < 32) buf[pos] = i;
    count += (int)__popcll(mk);
  }
  __syncthreads();
  if (lane < 32) {
    int cnt = count < 32 ? count : 32;
    int first = (count > 0) ? buf[0] : 0;
    int v = (lane < cnt) ? buf[lane] : first;
    nbidx[(size_t)gw * KNB + lane] = v;
  }
}

// ---------- MLP: lane=(kg,og) tile, acc[4 o][8 k], 3 LDS reads per channel ----------
__device__ __forceinline__ void layerT(const float* __restrict__ X,
                                       const float* __restrict__ W, int ldw, int cin,
                                       float4 bias, int og, int kg, float acc[4][8]) {
  const float bv[4] = {bias.x, bias.y, bias.z, bias.w};
#pragma unroll
  for (int oi = 0; oi < 4; ++oi)
#pragma unroll
    for (int ki = 0; ki < 8; ++ki) acc[oi][ki] = bv[oi];
#pragma unroll 4
  for (int c = 0; c < cin; ++c) {
    float4 xa = *(const float4*)(X + 32 * c + 8 * kg);       // 4 uniq addrs, bcast
    float4 xb = *(const float4*)(X + 32 * c + 8 * kg + 4);
    float4 w = *(const float4*)(W + ldw * c + 4 * og);       // 16 uniq, 2-way free
    const float wv[4] = {w.x, w.y, w.z, w.w};
    const float xv[8] = {xa.x, xa.y, xa.z, xa.w, xb.x, xb.y, xb.z, xb.w};
#pragma unroll
    for (int oi = 0; oi < 4; ++oi)
#pragma unroll
      for (int ki = 0; ki < 8; ++ki)
        acc[oi][ki] = fmaf(wv[oi], xv[ki], acc[oi][ki]);
  }
}

__device__ __forceinline__ void storeT(float* __restrict__ dst, int og, int kg,
                                       const float acc[4][8]) {
#pragma unroll
  for (int oi = 0; oi < 4; ++oi) {
    float4 va, vb;
    va.x = fmaxf(acc[oi][0], 0.f); va.y = fmaxf(acc[oi][1], 0.f);
    va.z = fmaxf(acc[oi][2], 0.f); va.w = fmaxf(acc[oi][3], 0.f);
    vb.x = fmaxf(acc[oi][4], 0.f); vb.y = fmaxf(acc[oi][5], 0.f);
    vb.z = fmaxf(acc[oi][6], 0.f); vb.w = fmaxf(acc[oi][7], 0.f);
    *(float4*)(dst + 32 * (4 * og + oi) + 8 * kg) = va;
    *(float4*)(dst + 32 * (4 * og + oi) + 8 * kg + 4) = vb;
  }
}

// one wave (64 threads) per center; X packed stride 32 in LDS; no barriers needed
// beyond intra-wave waitcnt (block == 1 wave)
__global__ __launch_bounds__(64) void mlp_kernel(const float* __restrict__ coords,
                                                 const float* __restrict__ featT,
                                                 const float* __restrict__ Wt,
                                                 const float* __restrict__ b1,
                                                 const float* __restrict__ b2,
                                                 const float* __restrict__ b3,
                                                 const int* __restrict__ cidx,
                                                 const int* __restrict__ nbidx,
                                                 float* __restrict__ outT) {
  const int g = blockIdx.x;
  const int b = g >> 11;
  const int lane = threadIdx.x;
  const int og = lane & 15, kg = lane >> 4;
  __shared__ __align__(16) float A[64 * 32];
  __shared__ __align__(16) float Bf[64 * 32];
  const float* C = coords + (size_t)b * 3 * NPTS;
  const int ci = cidx[g];
  const float ccx = C[ci], ccy = C[NPTS + ci], ccz = C[2 * NPTS + ci];
  const int* nb = nbidx + (size_t)g * KNB;
  if (lane < 32) {
    const int n = nb[lane];
    A[0 * 32 + lane] = C[n] - ccx;
    A[1 * 32 + lane] = C[NPTS + n] - ccy;
    A[2 * 32 + lane] = C[2 * NPTS + n] - ccz;
    const float4* f = (const float4*)(featT + ((size_t)b * NPTS + n) * 32);
#pragma unroll
    for (int q = 0; q < 4; ++q) {
      float4 v = f[q];
      A[(3 + 4 * q) * 32 + lane] = v.x;
      A[(4 + 4 * q) * 32 + lane] = v.y;
      A[(5 + 4 * q) * 32 + lane] = v.z;
      A[(6 + 4 * q) * 32 + lane] = v.w;
    }
  } else {
    const int k = lane - 32;
    const int n = nb[k];
    const float4* f = (const float4*)(featT + ((size_t)b * NPTS + n) * 32);
#pragma unroll
    for (int q = 4; q < 8; ++q) {
      float4 v = f[q];
      A[(3 + 4 * q) * 32 + k] = v.x;
      A[(4 + 4 * q) * 32 + k] = v.y;
      A[(5 + 4 * q) * 32 + k] = v.z;
      A[(6 + 4 * q) * 32 + k] = v.w;
    }
  }
  __syncthreads();
  float acc[4][8];
  // layer 1: 35 -> 64
  layerT(A, Wt, 64, 35, *(const float4*)(b1 + 4 * og), og, kg, acc);
  storeT(Bf, og, kg, acc);
  __syncthreads();
  // layer 2: 64 -> 64
  layerT(Bf, Wt + 2240, 64, 64, *(const float4*)(b2 + 4 * og), og, kg, acc);
  storeT(A, og, kg, acc);
  __syncthreads();
  // layer 3: 64 -> 128, two halves, maxpool over k (relu folded: max with 0)
  float* outp = outT + (size_t)g * 128;
#pragma unroll 1
  for (int h = 0; h < 2; ++h) {
    layerT(A, Wt + 6336 + 64 * h, 128, 64, *(const float4*)(b3 + 64 * h + 4 * og), og,
           kg, acc);
    float4 res;
    float* rp = (float*)&res;
#pragma unroll
    for (int oi = 0; oi < 4; ++oi) {
      float m = 0.f;
#pragma unroll
      for (int ki = 0; ki < 8; ++ki) m = fmaxf(m, acc[oi][ki]);
      m = fmaxf(m, __shfl_xor(m, 16));
      m = fmaxf(m, __shfl_xor(m, 32));
      rp[oi] = m;
    }
    if (kg == 0) *(float4*)(outp + 64 * h + 4 * og) = res;
  }
}

// ---------- output transpose (B,M,128) -> (B,128,M) ----------
__global__ __launch_bounds__(256) void outT_kernel(const float* __restrict__ outT,
                                                   float* __restrict__ out) {
  const int bid = blockIdx.x;
  const int b = bid >> 8;
  const int r = bid & 255;
  const int o0 = (r >> 6) * 32;
  const int m0 = (r & 63) * 32;
  __shared__ float tile[32][33];
  const int tx = threadIdx.x & 31, ty = threadIdx.x >> 5;
  const float* src = outT + ((size_t)b * MCTR + m0) * 128;
#pragma unroll
  for (int s = 0; s < 4; ++s) {
    int m = ty + 8 * s;
    tile[m][tx] = src[(size_t)m * 128 + o0 + tx];
  }
  __syncthreads();
  float* dst = out + ((size_t)b * 128 + o0) * MCTR + m0;
#pragma unroll
  for (int s = 0; s < 4; ++s) {
    int o = ty + 8 * s;
    dst[(size_t)o * MCTR + tx] = tile[tx][o];
  }
}

extern "C" void kernel_launch(void* const* d_in, const int* in_sizes, int n_in,
                              void* d_out, int out_size, void* d_ws, size_t ws_size,
                              hipStream_t stream) {
  (void)in_sizes; (void)n_in; (void)out_size; (void)ws_size;
  const float* feats = (const float*)d_in[0];
  const float* coords = (const float*)d_in[1];
  const float* W1 = (const float*)d_in[2];
  const float* b1 = (const float*)d_in[3];
  const float* W2 = (const float*)d_in[4];
  const float* b2 = (const float*)d_in[5];
  const float* W3 = (const float*)d_in[6];
  const float* b3 = (const float*)d_in[7];
  float* out = (float*)d_out;
  float* centers = out + (size_t)BATCH * 128 * MCTR;

  float* ws_f = (float*)d_ws;
  float* featT = ws_f;                                     // 1,048,576 f
  float* Wt = ws_f + 1048576;                              //    14,528 f
  int* cidx = (int*)(ws_f + 1048576 + 14528);              //     8,192 i
  int* nbidx = (int*)(ws_f + 1048576 + 14528 + 8192);      //   262,144 i
  float* outTbuf = ws_f + 1048576 + 14528 + 8192 + 262144; // 1,048,576 f
  // sorted-coord arrays overlay outTbuf: dead before mlp_kernel writes it
  float* sX = outTbuf;                 // 32768 f
  float* sY = outTbuf + 32768;         // 32768 f
  float* sZ = outTbuf + 65536;         // 32768 f
  int* sOrig = (int*)(outTbuf + 98304);// 32768 i

  featT_kernel<<<1024, 256, 0, stream>>>(feats, featT);
  prep_kernel<<<32, 256, 0, stream>>>(W1, W2, W3, Wt);
  xsort_kernel<<<BATCH, 512, 0, stream>>>(coords, sX, sY, sZ, sOrig);
  fps_kernel<<<BATCH, 512, 0, stream>>>(sX, sY, sZ, sOrig, cidx, centers);
  ballq_kernel<<<2048, 256, 0, stream>>>(coords, cidx, nbidx);
  mlp_kernel<<<BATCH * MCTR, 64, 0, stream>>>(coords, featT, Wt, b1, b2, b3, cidx, nbidx, outTbuf);
  outT_kernel<<<1024, 256, 0, stream>>>(outTbuf, out);
}

// Round 11
// 1831.149 us; speedup vs baseline: 1.7223x; 1.0795x over previous
//
#include <hip/hip_runtime.h>
#include <cstdint>
#include <cstddef>

#define NPTS 8192
#define MCTR 2048
#define BATCH 4
#define KNB 32

// ---- u32 wave max via DPP (identity 0, values >= 0), foldable to v_max_u32_dpp.
// row_shr:N pushes data to HIGHER lanes; max accumulates in lane 63. ----
__device__ __forceinline__ unsigned wave_max_u32(unsigned x) {
  unsigned t;
  t = (unsigned)__builtin_amdgcn_update_dpp(0, (int)x, 0x111, 0xf, 0xf, false);
  x = x > t ? x : t;
  t = (unsigned)__builtin_amdgcn_update_dpp(0, (int)x, 0x112, 0xf, 0xf, false);
  x = x > t ? x : t;
  t = (unsigned)__builtin_amdgcn_update_dpp(0, (int)x, 0x114, 0xf, 0xf, false);
  x = x > t ? x : t;
  t = (unsigned)__builtin_amdgcn_update_dpp(0, (int)x, 0x118, 0xf, 0xf, false);
  x = x > t ? x : t;
  t = (unsigned)__builtin_amdgcn_update_dpp(0, (int)x, 0x142, 0xa, 0xf, false);
  x = x > t ? x : t;
  t = (unsigned)__builtin_amdgcn_update_dpp(0, (int)x, 0x143, 0xc, 0xf, false);
  x = x > t ? x : t;
  return (unsigned)__builtin_amdgcn_readlane((int)x, 63);
}

// ---- u32 max over lanes 0..7 (accumulates in lane 7), broadcast ----
__device__ __forceinline__ unsigned oct_max_u32(unsigned x) {
  unsigned t;
  t = (unsigned)__builtin_amdgcn_update_dpp(0, (int)x, 0x114, 0xf, 0xf, false);
  x = x > t ? x : t;
  t = (unsigned)__builtin_amdgcn_update_dpp(0, (int)x, 0x112, 0xf, 0xf, false);
  x = x > t ? x : t;
  t = (unsigned)__builtin_amdgcn_update_dpp(0, (int)x, 0x111, 0xf, 0xf, false);
  x = x > t ? x : t;
  return (unsigned)__builtin_amdgcn_readlane((int)x, 7);
}

// ---------- feature transpose (B,32,N) -> (B,N,32) ----------
__global__ __launch_bounds__(256) void featT_kernel(const float* __restrict__ feats,
                                                    float* __restrict__ featT) {
  const int bn = blockIdx.x;
  const int b = bn >> 8;
  const int n0 = (bn & 255) * 32;
  __shared__ float tile[32][33];
  const int tx = threadIdx.x & 31, ty = threadIdx.x >> 5;
  const float* src = feats + (size_t)b * 32 * NPTS;
#pragma unroll
  for (int s = 0; s < 4; ++s) {
    int f = ty + 8 * s;
    tile[f][tx] = src[(size_t)f * NPTS + n0 + tx];
  }
  __syncthreads();
  float* dst = featT + ((size_t)b * NPTS + n0) * 32;
#pragma unroll
  for (int s = 0; s < 4; ++s) {
    int n = ty + 8 * s;
    dst[n * 32 + tx] = tile[tx][n];
  }
}

// ---------- weight transpose ----------
__global__ __launch_bounds__(256) void prep_kernel(const float* __restrict__ W1,
                                                   const float* __restrict__ W2,
                                                   const float* __restrict__ W3,
                                                   float* __restrict__ Wt) {
  const int t = blockIdx.x * 256 + threadIdx.x;
  if (t < 2240) { int c = t >> 6, o = t & 63;  Wt[t] = W1[o * 35 + c]; }
  if (t < 4096) { int c = t >> 6, o = t & 63;  Wt[2240 + t] = W2[o * 64 + c]; }
  if (t < 8192) { int c = t >> 7, o = t & 127; Wt[6336 + t] = W3[o * 64 + c]; }
}

// ---------- counting sort by x-bucket (512 buckets), one block per batch ----------
__global__ __launch_bounds__(512) void xsort_kernel(const float* __restrict__ coords,
                                                    float* __restrict__ sX,
                                                    float* __restrict__ sY,
                                                    float* __restrict__ sZ,
                                                    int* __restrict__ sOrig) {
  const int b = blockIdx.x;
  const int tid = threadIdx.x;
  const float* C = coords + (size_t)b * 3 * NPTS;
  __shared__ int h[512];
  __shared__ int cur[512];
  h[tid] = 0;
  __syncthreads();
  int bk[16];
#pragma unroll
  for (int j = 0; j < 16; ++j) {
    int i = tid + j * 512;
    float x = C[i];
    int k = (int)(x * 512.0f);
    k = k < 0 ? 0 : (k > 511 ? 511 : k);
    bk[j] = k;
    atomicAdd(&h[k], 1);
  }
  __syncthreads();
  const int cnt = h[tid];
  for (int s = 1; s < 512; s <<= 1) {
    int v = (tid >= s) ? h[tid - s] : 0;
    __syncthreads();
    h[tid] += v;
    __syncthreads();
  }
  cur[tid] = h[tid] - cnt;
  __syncthreads();
  float* dX = sX + (size_t)b * NPTS;
  float* dY = sY + (size_t)b * NPTS;
  float* dZ = sZ + (size_t)b * NPTS;
  int* dO = sOrig + (size_t)b * NPTS;
#pragma unroll
  for (int j = 0; j < 16; ++j) {
    int i = tid + j * 512;
    int pos = atomicAdd(&cur[bk[j]], 1);
    dX[pos] = C[i];
    dY[pos] = C[NPTS + i];
    dZ[pos] = C[2 * NPTS + i];
    dO[pos] = i;
  }
}

// ---------- furthest point sampling: blocked ownership + exact bbox culling ----------
// Two-phase foldable DPP reduces: (1) u32 max of dist bits (>=0 so bit order ==
// value order), (2) u32 max of 26-bit tail ((8191-orig)<<13|slot) among achievers
// -> exact (max dist, min ORIGINAL idx) == jnp.argmax first occurrence.
// Centroid fetch = wave-uniform ds_read_b128 broadcast. No global ops in loop.
__global__ __launch_bounds__(512) void fps_kernel(const float* __restrict__ sX,
                                                  const float* __restrict__ sY,
                                                  const float* __restrict__ sZ,
                                                  const int* __restrict__ sOrig,
                                                  int* __restrict__ cidx,
                                                  float* __restrict__ centers) {
  const int b = blockIdx.x;
  const int tid = threadIdx.x;
  const int wave = tid >> 6, lane = tid & 63;
  __shared__ __align__(16) float4 lC4[NPTS];  // 128 KiB
  __shared__ __align__(16) unsigned long long skey[2][8];
  __shared__ int s_slot0;
  const float* gX = sX + (size_t)b * NPTS;
  const float* gY = sY + (size_t)b * NPTS;
  const float* gZ = sZ + (size_t)b * NPTS;
  const int* gO = sOrig + (size_t)b * NPTS;
  for (int i = tid; i < NPTS; i += 512) {
    float4 v;
    v.x = gX[i]; v.y = gY[i]; v.z = gZ[i]; v.w = 0.0f;
    lC4[i] = v;
  }
  const int base = tid * 16;
  int og[16];
#pragma unroll
  for (int j = 0; j < 16; ++j) {
    og[j] = gO[base + j];
    if (og[j] == 0) s_slot0 = base + j;  // exactly one thread writes
  }
  __syncthreads();
  float px[16], py[16], pz[16], dd[16];
#pragma unroll
  for (int j = 0; j < 16; ++j) {
    float4 c = lC4[base + j];
    px[j] = c.x; py[j] = c.y; pz[j] = c.z;
    dd[j] = __builtin_inff();
  }
  // exact bbox of owned points
  float xlo = px[0], xhi = px[0], ylo = py[0], yhi = py[0], zlo = pz[0], zhi = pz[0];
#pragma unroll
  for (int j = 1; j < 16; ++j) {
    xlo = fminf(xlo, px[j]); xhi = fmaxf(xhi, px[j]);
    ylo = fminf(ylo, py[j]); yhi = fmaxf(yhi, py[j]);
    zlo = fminf(zlo, pz[j]); zhi = fmaxf(zhi, pz[j]);
  }
  float cmax = __builtin_inff();
  int amin17 = (og[0] << 4) | 0;
#pragma unroll
  for (int j = 1; j < 16; ++j) amin17 = min(amin17, (og[j] << 4) | j);
  const int slot0 = s_slot0;
  float4 cc = lC4[slot0];
  float cx = cc.x, cy = cc.y, cz = cc.z;
  unsigned long long wkey = 0;
  unsigned long long kreg[4];
  if (tid == 0)  // m=0: initial point, orig 0 (dist bits unused by writeback)
    kreg[0] = ((unsigned long long)(unsigned)8191 << 13) | (unsigned)slot0;
  int buf = 0;
  for (int it = 0; it < MCTR; ++it) {
    float dxm = fmaxf(fmaxf(xlo - cx, cx - xhi), 0.0f);
    float dym = fmaxf(fmaxf(ylo - cy, cy - yhi), 0.0f);
    float dzm = fmaxf(fmaxf(zlo - cz, cz - zhi), 0.0f);
    float lb = dxm * dxm + dym * dym + dzm * dzm;
    bool active = !(lb * 0.999999f >= cmax);  // margin makes skip provably exact
    unsigned long long mk = __ballot(active ? 1 : 0);
    if (mk != 0ull) {
      if (active) {
#pragma unroll
        for (int j = 0; j < 16; ++j) {
          // EXACT reference order: (dx*dx + dy*dy) + dz*dz, rn each step, no FMA
          float dx = __fsub_rn(px[j], cx);
          float dy = __fsub_rn(py[j], cy);
          float dz = __fsub_rn(pz[j], cz);
          float d = __fadd_rn(__fadd_rn(__fmul_rn(dx, dx), __fmul_rn(dy, dy)),
                              __fmul_rn(dz, dz));
          dd[j] = fminf(dd[j], d);
        }
        float a0 = fmaxf(fmaxf(dd[0], dd[1]), dd[2]);
        float a1 = fmaxf(fmaxf(dd[3], dd[4]), dd[5]);
        float a2 = fmaxf(fmaxf(dd[6], dd[7]), dd[8]);
        float a3 = fmaxf(fmaxf(dd[9], dd[10]), dd[11]);
        float a4 = fmaxf(fmaxf(dd[12], dd[13]), dd[14]);
        cmax = fmaxf(fmaxf(fmaxf(a0, a1), a2), fmaxf(fmaxf(a3, a4), dd[15]));
        amin17 = 0x7fffffff;  // min ORIGINAL idx among achievers of cmax
#pragma unroll
        for (int j = 0; j < 16; ++j)
          amin17 = min(amin17, (dd[j] == cmax) ? ((og[j] << 4) | j) : 0x7fffffff);
      }
      const unsigned mydist = __float_as_uint(cmax);
      const unsigned mytail =
          ((unsigned)(8191 - (amin17 >> 4)) << 13) | (unsigned)(base + (amin17 & 15));
      const unsigned gwd = wave_max_u32(mydist);               // phase A: dist
      const unsigned gwt = wave_max_u32(mydist == gwd ? mytail : 0u);  // phase B: tail
      wkey = ((unsigned long long)gwd << 32) | gwt;
      if (lane == 0) skey[buf][wave] = wkey;
    } else {
      if (lane == 0) skey[buf][wave] = wkey;  // nothing changed in this wave
    }
    __syncthreads();
    // cross-wave: 1 multicast b64 read + two 3-step foldable DPP reduces
    const unsigned long long kc = skey[buf][lane & 7];
    const unsigned kd = (unsigned)(kc >> 32), kt = (unsigned)kc;
    const unsigned gd = oct_max_u32(kd);
    const unsigned gt = oct_max_u32(kd == gd ? kt : 0u);
    const unsigned long long gk = ((unsigned long long)gd << 32) | gt;
    if (((it + 1) >> 2) == tid) kreg[(it + 1) & 3] = gk;  // winner for m=it+1
    const int slot = (int)(gt & 0x1fff);
    float4 c2 = lC4[slot];  // ONE ds_read_b128, wave-uniform broadcast
    cx = c2.x; cy = c2.y; cz = c2.z;
    buf ^= 1;
  }
  // coalesced writeback: thread t owns centers m = 4t..4t+3
#pragma unroll
  for (int r = 0; r < 4; ++r) {
    unsigned long long k = kreg[r];
    int orig = 8191 - (int)((k >> 13) & 0x1fff);
    int sl = (int)(k & 0x1fff);
    int m = 4 * tid + r;
    float4 c = lC4[sl];
    cidx[b * MCTR + m] = orig;
    centers[(size_t)b * 3 * MCTR + m] = c.x;
    centers[(size_t)b * 3 * MCTR + MCTR + m] = c.y;
    centers[(size_t)b * 3 * MCTR + 2 * MCTR + m] = c.z;
  }
}

// ---------- ball query: one wave per center, software-pipelined loads ----------
__global__ __launch_bounds__(256) void ballq_kernel(const float* __restrict__ coords,
                                                    const int* __restrict__ cidx,
                                                    int* __restrict__ nbidx) {
  const int wib = threadIdx.x >> 6;
  const int gw = blockIdx.x * 4 + wib;
  const int lane = threadIdx.x & 63;
  const int b = gw >> 11;
  const float* C = coords + (size_t)b * 3 * NPTS;
  const int ci = cidx[gw];
  const float cx = C[ci], cy = C[NPTS + ci], cz = C[2 * NPTS + ci];
  // python double 0.2*0.2 demoted to f32 == 0x3D23D70A (NOT 0.2f*0.2f!)
  const float R2 = (float)(0.2 * 0.2);
  __shared__ int sbuf[4][32];
  int* buf = sbuf[wib];
  int count = 0;
  float xx = C[lane], yy = C[NPTS + lane], zz = C[2 * NPTS + lane];
  for (int base = 0; base < NPTS && count < 32; base += 64) {
    float nx = 0.f, ny = 0.f, nz = 0.f;
    if (base + 64 < NPTS) {  // prefetch next round while this round resolves
      const int ni = base + 64 + lane;
      nx = C[ni]; ny = C[NPTS + ni]; nz = C[2 * NPTS + ni];
    }
    float dx = __fsub_rn(cx, xx);
    float dy = __fsub_rn(cy, yy);
    float dz = __fsub_rn(cz, zz);
    float d2 = __fadd_rn(__fadd_rn(__fmul_rn(dx, dx), __fmul_rn(dy, dy)), __fmul_rn(dz, dz));
    bool q = d2 < R2;
    unsigned long long mk = __ballot(q ? 1 : 0);
    int pos = count + (int)__popcll(mk & ((1ull << lane) - 1ull));
    if (q && pos < 32) buf[pos] = base + lane;
    count += (int)__popcll(mk);
    xx = nx; yy = ny; zz = nz;
  }
  __syncthreads();
  if (lane < 32) {
    int cnt = count < 32 ? count : 32;
    int first = (count > 0) ? buf[0] : 0;
    int v = (lane < cnt) ? buf[lane] : first;
    nbidx[(size_t)gw * KNB + lane] = v;
  }
}

// ---------- MLP: lane=(kg,og) tile, acc[4 o][8 k], 3 LDS reads per channel ----------
__device__ __forceinline__ void layerT(const float* __restrict__ X,
                                       const float* __restrict__ W, int ldw, int cin,
                                       float4 bias, int og, int kg, float acc[4][8]) {
  const float bv[4] = {bias.x, bias.y, bias.z, bias.w};
#pragma unroll
  for (int oi = 0; oi < 4; ++oi)
#pragma unroll
    for (int ki = 0; ki < 8; ++ki) acc[oi][ki] = bv[oi];
#pragma unroll 4
  for (int c = 0; c < cin; ++c) {
    float4 xa = *(const float4*)(X + 32 * c + 8 * kg);       // 4 uniq addrs, bcast
    float4 xb = *(const float4*)(X + 32 * c + 8 * kg + 4);
    float4 w = *(const float4*)(W + ldw * c + 4 * og);       // 16 uniq, 2-way free
    const float wv[4] = {w.x, w.y, w.z, w.w};
    const float xv[8] = {xa.x, xa.y, xa.z, xa.w, xb.x, xb.y, xb.z, xb.w};
#pragma unroll
    for (int oi = 0; oi < 4; ++oi)
#pragma unroll
      for (int ki = 0; ki < 8; ++ki)
        acc[oi][ki] = fmaf(wv[oi], xv[ki], acc[oi][ki]);
  }
}

__device__ __forceinline__ void storeT(float* __restrict__ dst, int og, int kg,
                                       const float acc[4][8]) {
#pragma unroll
  for (int oi = 0; oi < 4; ++oi) {
    float4 va, vb;
    va.x = fmaxf(acc[oi][0], 0.f); va.y = fmaxf(acc[oi][1], 0.f);
    va.z = fmaxf(acc[oi][2], 0.f); va.w = fmaxf(acc[oi][3], 0.f);
    vb.x = fmaxf(acc[oi][4], 0.f); vb.y = fmaxf(acc[oi][5], 0.f);
    vb.z = fmaxf(acc[oi][6], 0.f); vb.w = fmaxf(acc[oi][7], 0.f);
    *(float4*)(dst + 32 * (4 * og + oi) + 8 * kg) = va;
    *(float4*)(dst + 32 * (4 * og + oi) + 8 * kg + 4) = vb;
  }
}

// one wave (64 threads) per center; X packed stride 32 in LDS
__global__ __launch_bounds__(64) void mlp_kernel(const float* __restrict__ coords,
                                                 const float* __restrict__ featT,
                                                 const float* __restrict__ Wt,
                                                 const float* __restrict__ b1,
                                                 const float* __restrict__ b2,
                                                 const float* __restrict__ b3,
                                                 const int* __restrict__ cidx,
                                                 const int* __restrict__ nbidx,
                                                 float* __restrict__ outT) {
  const int g = blockIdx.x;
  const int b = g >> 11;
  const int lane = threadIdx.x;
  const int og = lane & 15, kg = lane >> 4;
  __shared__ __align__(16) float A[64 * 32];
  __shared__ __align__(16) float Bf[64 * 32];
  const float* C = coords + (size_t)b * 3 * NPTS;
  const int ci = cidx[g];
  const float ccx = C[ci], ccy = C[NPTS + ci], ccz = C[2 * NPTS + ci];
  const int* nb = nbidx + (size_t)g * KNB;
  if (lane < 32) {
    const int n = nb[lane];
    A[0 * 32 + lane] = C[n] - ccx;
    A[1 * 32 + lane] = C[NPTS + n] - ccy;
    A[2 * 32 + lane] = C[2 * NPTS + n] - ccz;
    const float4* f = (const float4*)(featT + ((size_t)b * NPTS + n) * 32);
#pragma unroll
    for (int q = 0; q < 4; ++q) {
      float4 v = f[q];
      A[(3 + 4 * q) * 32 + lane] = v.x;
      A[(4 + 4 * q) * 32 + lane] = v.y;
      A[(5 + 4 * q) * 32 + lane] = v.z;
      A[(6 + 4 * q) * 32 + lane] = v.w;
    }
  } else {
    const int k = lane - 32;
    const int n = nb[k];
    const float4* f = (const float4*)(featT + ((size_t)b * NPTS + n) * 32);
#pragma unroll
    for (int q = 4; q < 8; ++q) {
      float4 v = f[q];
      A[(3 + 4 * q) * 32 + k] = v.x;
      A[(4 + 4 * q) * 32 + k] = v.y;
      A[(5 + 4 * q) * 32 + k] = v.z;
      A[(6 + 4 * q) * 32 + k] = v.w;
    }
  }
  __syncthreads();
  float acc[4][8];
  layerT(A, Wt, 64, 35, *(const float4*)(b1 + 4 * og), og, kg, acc);
  storeT(Bf, og, kg, acc);
  __syncthreads();
  layerT(Bf, Wt + 2240, 64, 64, *(const float4*)(b2 + 4 * og), og, kg, acc);
  storeT(A, og, kg, acc);
  __syncthreads();
  float* outp = outT + (size_t)g * 128;
#pragma unroll 1
  for (int h = 0; h < 2; ++h) {
    layerT(A, Wt + 6336 + 64 * h, 128, 64, *(const float4*)(b3 + 64 * h + 4 * og), og,
           kg, acc);
    float4 res;
    float* rp = (float*)&res;
#pragma unroll
    for (int oi = 0; oi < 4; ++oi) {
      float m = 0.f;
#pragma unroll
      for (int ki = 0; ki < 8; ++ki) m = fmaxf(m, acc[oi][ki]);
      m = fmaxf(m, __shfl_xor(m, 16));
      m = fmaxf(m, __shfl_xor(m, 32));
      rp[oi] = m;
    }
    if (kg == 0) *(float4*)(outp + 64 * h + 4 * og) = res;
  }
}

// ---------- output transpose (B,M,128) -> (B,128,M) ----------
__global__ __launch_bounds__(256) void outT_kernel(const float* __restrict__ outT,
                                                   float* __restrict__ out) {
  const int bid = blockIdx.x;
  const int b = bid >> 8;
  const int r = bid & 255;
  const int o0 = (r >> 6) * 32;
  const int m0 = (r & 63) * 32;
  __shared__ float tile[32][33];
  const int tx = threadIdx.x & 31, ty = threadIdx.x >> 5;
  const float* src = outT + ((size_t)b * MCTR + m0) * 128;
#pragma unroll
  for (int s = 0; s < 4; ++s) {
    int m = ty + 8 * s;
    tile[m][tx] = src[(size_t)m * 128 + o0 + tx];
  }
  __syncthreads();
  float* dst = out + ((size_t)b * 128 + o0) * MCTR + m0;
#pragma unroll
  for (int s = 0; s < 4; ++s) {
    int o = ty + 8 * s;
    dst[(size_t)o * MCTR + tx] = tile[tx][o];
  }
}

extern "C" void kernel_launch(void* const* d_in, const int* in_sizes, int n_in,
                              void* d_out, int out_size, void* d_ws, size_t ws_size,
                              hipStream_t stream) {
  (void)in_sizes; (void)n_in; (void)out_size; (void)ws_size;
  const float* feats = (const float*)d_in[0];
  const float* coords = (const float*)d_in[1];
  const float* W1 = (const float*)d_in[2];
  const float* b1 = (const float*)d_in[3];
  const float* W2 = (const float*)d_in[4];
  const float* b2 = (const float*)d_in[5];
  const float* W3 = (const float*)d_in[6];
  const float* b3 = (const float*)d_in[7];
  float* out = (float*)d_out;
  float* centers = out + (size_t)BATCH * 128 * MCTR;

  float* ws_f = (float*)d_ws;
  float* featT = ws_f;                                     // 1,048,576 f
  float* Wt = ws_f + 1048576;                              //    14,528 f
  int* cidx = (int*)(ws_f + 1048576 + 14528);              //     8,192 i
  int* nbidx = (int*)(ws_f + 1048576 + 14528 + 8192);      //   262,144 i
  float* outTbuf = ws_f + 1048576 + 14528 + 8192 + 262144; // 1,048,576 f
  // sorted-coord arrays overlay outTbuf: dead before mlp_kernel writes it
  float* sX = outTbuf;                 // 32768 f
  float* sY = outTbuf + 32768;         // 32768 f
  float* sZ = outTbuf + 65536;         // 32768 f
  int* sOrig = (int*)(outTbuf + 98304);// 32768 i

  featT_kernel<<<1024, 256, 0, stream>>>(feats, featT);
  prep_kernel<<<32, 256, 0, stream>>>(W1, W2, W3, Wt);
  xsort_kernel<<<BATCH, 512, 0, stream>>>(coords, sX, sY, sZ, sOrig);
  fps_kernel<<<BATCH, 512, 0, stream>>>(sX, sY, sZ, sOrig, cidx, centers);
  ballq_kernel<<<2048, 256, 0, stream>>>(coords, cidx, nbidx);
  mlp_kernel<<<BATCH * MCTR, 64, 0, stream>>>(coords, featT, Wt, b1, b2, b3, cidx, nbidx, outTbuf);
  outT_kernel<<<1024, 256, 0, stream>>>(outTbuf, out);
}

// Round 12
// 1790.768 us; speedup vs baseline: 1.7611x; 1.0225x over previous
//
#include <hip/hip_runtime.h>
#include <cstdint>
#include <cstddef>

#define NPTS 8192
#define MCTR 2048
#define BATCH 4
#define KNB 32

typedef float v2f __attribute__((ext_vector_type(2)));

// ---- u32 wave max via DPP (identity 0, values >= 0), foldable to v_max_u32_dpp.
// row_shr:N pushes data to HIGHER lanes; max accumulates in lane 63. ----
__device__ __forceinline__ unsigned wave_max_u32(unsigned x) {
  unsigned t;
  t = (unsigned)__builtin_amdgcn_update_dpp(0, (int)x, 0x111, 0xf, 0xf, false);
  x = x > t ? x : t;
  t = (unsigned)__builtin_amdgcn_update_dpp(0, (int)x, 0x112, 0xf, 0xf, false);
  x = x > t ? x : t;
  t = (unsigned)__builtin_amdgcn_update_dpp(0, (int)x, 0x114, 0xf, 0xf, false);
  x = x > t ? x : t;
  t = (unsigned)__builtin_amdgcn_update_dpp(0, (int)x, 0x118, 0xf, 0xf, false);
  x = x > t ? x : t;
  t = (unsigned)__builtin_amdgcn_update_dpp(0, (int)x, 0x142, 0xa, 0xf, false);
  x = x > t ? x : t;
  t = (unsigned)__builtin_amdgcn_update_dpp(0, (int)x, 0x143, 0xc, 0xf, false);
  x = x > t ? x : t;
  return (unsigned)__builtin_amdgcn_readlane((int)x, 63);
}

// ---- u32 max over lanes 0..7 (accumulates in lane 7), broadcast ----
__device__ __forceinline__ unsigned oct_max_u32(unsigned x) {
  unsigned t;
  t = (unsigned)__builtin_amdgcn_update_dpp(0, (int)x, 0x114, 0xf, 0xf, false);
  x = x > t ? x : t;
  t = (unsigned)__builtin_amdgcn_update_dpp(0, (int)x, 0x112, 0xf, 0xf, false);
  x = x > t ? x : t;
  t = (unsigned)__builtin_amdgcn_update_dpp(0, (int)x, 0x111, 0xf, 0xf, false);
  x = x > t ? x : t;
  return (unsigned)__builtin_amdgcn_readlane((int)x, 7);
}

// ---------- feature transpose (B,32,N) -> (B,N,32) ----------
__global__ __launch_bounds__(256) void featT_kernel(const float* __restrict__ feats,
                                                    float* __restrict__ featT) {
  const int bn = blockIdx.x;
  const int b = bn >> 8;
  const int n0 = (bn & 255) * 32;
  __shared__ float tile[32][33];
  const int tx = threadIdx.x & 31, ty = threadIdx.x >> 5;
  const float* src = feats + (size_t)b * 32 * NPTS;
#pragma unroll
  for (int s = 0; s < 4; ++s) {
    int f = ty + 8 * s;
    tile[f][tx] = src[(size_t)f * NPTS + n0 + tx];
  }
  __syncthreads();
  float* dst = featT + ((size_t)b * NPTS + n0) * 32;
#pragma unroll
  for (int s = 0; s < 4; ++s) {
    int n = ty + 8 * s;
    dst[n * 32 + tx] = tile[tx][n];
  }
}

// ---------- weight transpose ----------
__global__ __launch_bounds__(256) void prep_kernel(const float* __restrict__ W1,
                                                   const float* __restrict__ W2,
                                                   const float* __restrict__ W3,
                                                   float* __restrict__ Wt) {
  const int t = blockIdx.x * 256 + threadIdx.x;
  if (t < 2240) { int c = t >> 6, o = t & 63;  Wt[t] = W1[o * 35 + c]; }
  if (t < 4096) { int c = t >> 6, o = t & 63;  Wt[2240 + t] = W2[o * 64 + c]; }
  if (t < 8192) { int c = t >> 7, o = t & 127; Wt[6336 + t] = W3[o * 64 + c]; }
}

// ---------- counting sort by x-bucket (512 buckets), one block per batch ----------
__global__ __launch_bounds__(512) void xsort_kernel(const float* __restrict__ coords,
                                                    float* __restrict__ sX,
                                                    float* __restrict__ sY,
                                                    float* __restrict__ sZ,
                                                    int* __restrict__ sOrig) {
  const int b = blockIdx.x;
  const int tid = threadIdx.x;
  const float* C = coords + (size_t)b * 3 * NPTS;
  __shared__ int h[512];
  __shared__ int cur[512];
  h[tid] = 0;
  __syncthreads();
  int bk[16];
#pragma unroll
  for (int j = 0; j < 16; ++j) {
    int i = tid + j * 512;
    float x = C[i];
    int k = (int)(x * 512.0f);
    k = k < 0 ? 0 : (k > 511 ? 511 : k);
    bk[j] = k;
    atomicAdd(&h[k], 1);
  }
  __syncthreads();
  const int cnt = h[tid];
  for (int s = 1; s < 512; s <<= 1) {
    int v = (tid >= s) ? h[tid - s] : 0;
    __syncthreads();
    h[tid] += v;
    __syncthreads();
  }
  cur[tid] = h[tid] - cnt;
  __syncthreads();
  float* dX = sX + (size_t)b * NPTS;
  float* dY = sY + (size_t)b * NPTS;
  float* dZ = sZ + (size_t)b * NPTS;
  int* dO = sOrig + (size_t)b * NPTS;
#pragma unroll
  for (int j = 0; j < 16; ++j) {
    int i = tid + j * 512;
    int pos = atomicAdd(&cur[bk[j]], 1);
    dX[pos] = C[i];
    dY[pos] = C[NPTS + i];
    dZ[pos] = C[2 * NPTS + i];
    dO[pos] = i;
  }
}

// ---------- furthest point sampling: blocked ownership + exact bbox culling ----------
// Hot loop on ext_vector(2) with fp contract(off): v_pk_add/mul_f32 are IEEE-rn per
// half == scalar ops bit-exact; contraction disabled so (dx*dx+dy*dy)+dz*dz rounds
// exactly like the reference. Two-phase foldable DPP reduces (dist bits, then tail
// among achievers) give exact (max dist, min ORIGINAL idx) == jnp.argmax.
__global__ __launch_bounds__(512) void fps_kernel(const float* __restrict__ sX,
                                                  const float* __restrict__ sY,
                                                  const float* __restrict__ sZ,
                                                  const int* __restrict__ sOrig,
                                                  int* __restrict__ cidx,
                                                  float* __restrict__ centers) {
  const int b = blockIdx.x;
  const int tid = threadIdx.x;
  const int wave = tid >> 6, lane = tid & 63;
  __shared__ __align__(16) float4 lC4[NPTS];  // 128 KiB
  __shared__ __align__(16) unsigned long long skey[2][8];
  __shared__ int s_slot0;
  const float* gX = sX + (size_t)b * NPTS;
  const float* gY = sY + (size_t)b * NPTS;
  const float* gZ = sZ + (size_t)b * NPTS;
  const int* gO = sOrig + (size_t)b * NPTS;
  for (int i = tid; i < NPTS; i += 512) {
    float4 v;
    v.x = gX[i]; v.y = gY[i]; v.z = gZ[i]; v.w = 0.0f;
    lC4[i] = v;
  }
  const int base = tid * 16;
  int og[16];
#pragma unroll
  for (int j = 0; j < 16; ++j) {
    og[j] = gO[base + j];
    if (og[j] == 0) s_slot0 = base + j;  // exactly one thread writes
  }
  __syncthreads();
  v2f px[8], py[8], pz[8], dd[8];
#pragma unroll
  for (int p = 0; p < 8; ++p) {
    float4 c0 = lC4[base + 2 * p];
    float4 c1 = lC4[base + 2 * p + 1];
    px[p].x = c0.x; px[p].y = c1.x;
    py[p].x = c0.y; py[p].y = c1.y;
    pz[p].x = c0.z; pz[p].y = c1.z;
    dd[p].x = __builtin_inff(); dd[p].y = __builtin_inff();
  }
  // exact bbox of owned points
  v2f xl = px[0], xh = px[0], yl = py[0], yh = py[0], zl = pz[0], zh = pz[0];
#pragma unroll
  for (int p = 1; p < 8; ++p) {
    xl = __builtin_elementwise_min(xl, px[p]); xh = __builtin_elementwise_max(xh, px[p]);
    yl = __builtin_elementwise_min(yl, py[p]); yh = __builtin_elementwise_max(yh, py[p]);
    zl = __builtin_elementwise_min(zl, pz[p]); zh = __builtin_elementwise_max(zh, pz[p]);
  }
  const float xlo = fminf(xl.x, xl.y), xhi = fmaxf(xh.x, xh.y);
  const float ylo = fminf(yl.x, yl.y), yhi = fmaxf(yh.x, yh.y);
  const float zlo = fminf(zl.x, zl.y), zhi = fmaxf(zh.x, zh.y);
  float cmax = __builtin_inff();
  int amin17 = (og[0] << 4) | 0;
#pragma unroll
  for (int j = 1; j < 16; ++j) amin17 = min(amin17, (og[j] << 4) | j);
  const int slot0 = s_slot0;
  float4 cc = lC4[slot0];
  float cx = cc.x, cy = cc.y, cz = cc.z;
  unsigned long long wkey = 0;
  unsigned long long kreg[4];
  if (tid == 0)  // m=0: initial point, orig 0 (dist bits unused by writeback)
    kreg[0] = ((unsigned long long)(unsigned)8191 << 13) | (unsigned)slot0;
  int buf = 0;
  for (int it = 0; it < MCTR; ++it) {
    float dxm = fmaxf(fmaxf(xlo - cx, cx - xhi), 0.0f);
    float dym = fmaxf(fmaxf(ylo - cy, cy - yhi), 0.0f);
    float dzm = fmaxf(fmaxf(zlo - cz, cz - zhi), 0.0f);
    float lb = dxm * dxm + dym * dym + dzm * dzm;
    bool active = !(lb * 0.999999f >= cmax);  // margin makes skip provably exact
    unsigned long long mk = __ballot(active ? 1 : 0);
    if (mk != 0ull) {
      if (active) {
        v2f vcx, vcy, vcz;
        vcx.x = cx; vcx.y = cx;
        vcy.x = cy; vcy.y = cy;
        vcz.x = cz; vcz.y = cz;
        {
#pragma clang fp contract(off)
          // EXACT reference order per half: (dx*dx + dy*dy) + dz*dz, rn each
          // step, no FMA (contract off). Packed == scalar bit-exact.
#pragma unroll
          for (int p = 0; p < 8; ++p) {
            v2f dx = px[p] - vcx;
            v2f dy = py[p] - vcy;
            v2f dz = pz[p] - vcz;
            v2f d = (dx * dx + dy * dy) + dz * dz;
            dd[p] = __builtin_elementwise_min(dd[p], d);
          }
        }
        v2f m01 = __builtin_elementwise_max(dd[0], dd[1]);
        v2f m23 = __builtin_elementwise_max(dd[2], dd[3]);
        v2f m45 = __builtin_elementwise_max(dd[4], dd[5]);
        v2f m67 = __builtin_elementwise_max(dd[6], dd[7]);
        v2f m03 = __builtin_elementwise_max(m01, m23);
        v2f m47 = __builtin_elementwise_max(m45, m67);
        v2f mm = __builtin_elementwise_max(m03, m47);
        cmax = fmaxf(mm.x, mm.y);
        // min ORIGINAL idx among achievers — depth-4 tree (was 16-deep chain)
        int c0, c1, c2, c3, c4, c5, c6, c7;
        c0 = min(dd[0].x == cmax ? ((og[0] << 4) | 0) : 0x7fffffff,
                 dd[0].y == cmax ? ((og[1] << 4) | 1) : 0x7fffffff);
        c1 = min(dd[1].x == cmax ? ((og[2] << 4) | 2) : 0x7fffffff,
                 dd[1].y == cmax ? ((og[3] << 4) | 3) : 0x7fffffff);
        c2 = min(dd[2].x == cmax ? ((og[4] << 4) | 4) : 0x7fffffff,
                 dd[2].y == cmax ? ((og[5] << 4) | 5) : 0x7fffffff);
        c3 = min(dd[3].x == cmax ? ((og[6] << 4) | 6) : 0x7fffffff,
                 dd[3].y == cmax ? ((og[7] << 4) | 7) : 0x7fffffff);
        c4 = min(dd[4].x == cmax ? ((og[8] << 4) | 8) : 0x7fffffff,
                 dd[4].y == cmax ? ((og[9] << 4) | 9) : 0x7fffffff);
        c5 = min(dd[5].x == cmax ? ((og[10] << 4) | 10) : 0x7fffffff,
                 dd[5].y == cmax ? ((og[11] << 4) | 11) : 0x7fffffff);
        c6 = min(dd[6].x == cmax ? ((og[12] << 4) | 12) : 0x7fffffff,
                 dd[6].y == cmax ? ((og[13] << 4) | 13) : 0x7fffffff);
        c7 = min(dd[7].x == cmax ? ((og[14] << 4) | 14) : 0x7fffffff,
                 dd[7].y == cmax ? ((og[15] << 4) | 15) : 0x7fffffff);
        amin17 = min(min(min(c0, c1), min(c2, c3)), min(min(c4, c5), min(c6, c7)));
      }
      const unsigned mydist = __float_as_uint(cmax);
      const unsigned mytail =
          ((unsigned)(8191 - (amin17 >> 4)) << 13) | (unsigned)(base + (amin17 & 15));
      const unsigned gwd = wave_max_u32(mydist);                     // phase A
      const unsigned gwt = wave_max_u32(mydist == gwd ? mytail : 0u);  // phase B
      wkey = ((unsigned long long)gwd << 32) | gwt;
      if (lane == 0) skey[buf][wave] = wkey;
    } else {
      if (lane == 0) skey[buf][wave] = wkey;  // nothing changed in this wave
    }
    __syncthreads();
    // cross-wave: 1 multicast b64 read + two 3-step foldable DPP reduces
    const unsigned long long kc = skey[buf][lane & 7];
    const unsigned kd = (unsigned)(kc >> 32), kt = (unsigned)kc;
    const unsigned gd = oct_max_u32(kd);
    const unsigned gt = oct_max_u32(kd == gd ? kt : 0u);
    const unsigned long long gk = ((unsigned long long)gd << 32) | gt;
    if (((it + 1) >> 2) == tid) kreg[(it + 1) & 3] = gk;  // winner for m=it+1
    const int slot = (int)(gt & 0x1fff);
    float4 c2 = lC4[slot];  // ONE ds_read_b128, wave-uniform broadcast
    cx = c2.x; cy = c2.y; cz = c2.z;
    buf ^= 1;
  }
  // coalesced writeback: thread t owns centers m = 4t..4t+3
#pragma unroll
  for (int r = 0; r < 4; ++r) {
    unsigned long long k = kreg[r];
    int orig = 8191 - (int)((k >> 13) & 0x1fff);
    int sl = (int)(k & 0x1fff);
    int m = 4 * tid + r;
    float4 c = lC4[sl];
    cidx[b * MCTR + m] = orig;
    centers[(size_t)b * 3 * MCTR + m] = c.x;
    centers[(size_t)b * 3 * MCTR + MCTR + m] = c.y;
    centers[(size_t)b * 3 * MCTR + 2 * MCTR + m] = c.z;
  }
}

// ---------- ball query: one wave per center, software-pipelined loads ----------
__global__ __launch_bounds__(256) void ballq_kernel(const float* __restrict__ coords,
                                                    const int* __restrict__ cidx,
                                                    int* __restrict__ nbidx) {
  const int wib = threadIdx.x >> 6;
  const int gw = blockIdx.x * 4 + wib;
  const int lane = threadIdx.x & 63;
  const int b = gw >> 11;
  const float* C = coords + (size_t)b * 3 * NPTS;
  const int ci = cidx[gw];
  const float cx = C[ci], cy = C[NPTS + ci], cz = C[2 * NPTS + ci];
  // python double 0.2*0.2 demoted to f32 == 0x3D23D70A (NOT 0.2f*0.2f!)
  const float R2 = (float)(0.2 * 0.2);
  __shared__ int sbuf[4][32];
  int* buf = sbuf[wib];
  int count = 0;
  float xx = C[lane], yy = C[NPTS + lane], zz = C[2 * NPTS + lane];
  for (int base = 0; base < NPTS && count < 32; base += 64) {
    float nx = 0.f, ny = 0.f, nz = 0.f;
    if (base + 64 < NPTS) {  // prefetch next round while this round resolves
      const int ni = base + 64 + lane;
      nx = C[ni]; ny = C[NPTS + ni]; nz = C[2 * NPTS + ni];
    }
    float dx = __fsub_rn(cx, xx);
    float dy = __fsub_rn(cy, yy);
    float dz = __fsub_rn(cz, zz);
    float d2 = __fadd_rn(__fadd_rn(__fmul_rn(dx, dx), __fmul_rn(dy, dy)), __fmul_rn(dz, dz));
    bool q = d2 < R2;
    unsigned long long mk = __ballot(q ? 1 : 0);
    int pos = count + (int)__popcll(mk & ((1ull << lane) - 1ull));
    if (q && pos < 32) buf[pos] = base + lane;
    count += (int)__popcll(mk);
    xx = nx; yy = ny; zz = nz;
  }
  __syncthreads();
  if (lane < 32) {
    int cnt = count < 32 ? count : 32;
    int first = (count > 0) ? buf[0] : 0;
    int v = (lane < cnt) ? buf[lane] : first;
    nbidx[(size_t)gw * KNB + lane] = v;
  }
}

// ---------- MLP with XOR-swizzled LDS (kills 16-way write conflicts) ----------
// SW(ch,col): col XORed with 4-float block keyed on (ch>>2)&7 — preserves b128
// blocks (XOR by multiple of 4), spreads row-major writes across 8 bank-groups.
__device__ __forceinline__ int SW(int ch, int col) {
  return 32 * ch + (col ^ ((((ch) >> 2) & 7) << 2));
}

__device__ __forceinline__ void layerT(const float* __restrict__ X,
                                       const float* __restrict__ W, int ldw, int cin,
                                       float4 bias, int og, int kg, float acc[4][8]) {
  const float bv[4] = {bias.x, bias.y, bias.z, bias.w};
#pragma unroll
  for (int oi = 0; oi < 4; ++oi)
#pragma unroll
    for (int ki = 0; ki < 8; ++ki) acc[oi][ki] = bv[oi];
#pragma unroll 4
  for (int c = 0; c < cin; ++c) {
    const float4 xa = *(const float4*)(X + SW(c, 8 * kg));      // bcast, no conflict
    const float4 xb = *(const float4*)(X + SW(c, 8 * kg + 4));
    float4 w = *(const float4*)(W + ldw * c + 4 * og);          // global, coalesced
    const float wv[4] = {w.x, w.y, w.z, w.w};
    const float xv[8] = {xa.x, xa.y, xa.z, xa.w, xb.x, xb.y, xb.z, xb.w};
#pragma unroll
    for (int oi = 0; oi < 4; ++oi)
#pragma unroll
      for (int ki = 0; ki < 8; ++ki)
        acc[oi][ki] = fmaf(wv[oi], xv[ki], acc[oi][ki]);
  }
}

__device__ __forceinline__ void storeT(float* __restrict__ dst, int og, int kg,
                                       const float acc[4][8]) {
#pragma unroll
  for (int oi = 0; oi < 4; ++oi) {
    float4 va, vb;
    va.x = fmaxf(acc[oi][0], 0.f); va.y = fmaxf(acc[oi][1], 0.f);
    va.z = fmaxf(acc[oi][2], 0.f); va.w = fmaxf(acc[oi][3], 0.f);
    vb.x = fmaxf(acc[oi][4], 0.f); vb.y = fmaxf(acc[oi][5], 0.f);
    vb.z = fmaxf(acc[oi][6], 0.f); vb.w = fmaxf(acc[oi][7], 0.f);
    const int r = 4 * og + oi;
    *(float4*)(dst + SW(r, 8 * kg)) = va;      // 2-way max under swizzle (free)
    *(float4*)(dst + SW(r, 8 * kg + 4)) = vb;
  }
}

// one wave (64 threads) per center; X swizzled stride-32 in LDS
__global__ __launch_bounds__(64) void mlp_kernel(const float* __restrict__ coords,
                                                 const float* __restrict__ featT,
                                                 const float* __restrict__ Wt,
                                                 const float* __restrict__ b1,
                                                 const float* __restrict__ b2,
                                                 const float* __restrict__ b3,
                                                 const int* __restrict__ cidx,
                                                 const int* __restrict__ nbidx,
                                                 float* __restrict__ outT) {
  const int g = blockIdx.x;
  const int b = g >> 11;
  const int lane = threadIdx.x;
  const int og = lane & 15, kg = lane >> 4;
  __shared__ __align__(16) float A[64 * 32];
  __shared__ __align__(16) float Bf[64 * 32];
  const float* C = coords + (size_t)b * 3 * NPTS;
  const int ci = cidx[g];
  const float ccx = C[ci], ccy = C[NPTS + ci], ccz = C[2 * NPTS + ci];
  const int* nb = nbidx + (size_t)g * KNB;
  if (lane < 32) {
    const int n = nb[lane];
    A[SW(0, lane)] = C[n] - ccx;
    A[SW(1, lane)] = C[NPTS + n] - ccy;
    A[SW(2, lane)] = C[2 * NPTS + n] - ccz;
    const float4* f = (const float4*)(featT + ((size_t)b * NPTS + n) * 32);
#pragma unroll
    for (int q = 0; q < 4; ++q) {
      float4 v = f[q];
      A[SW(3 + 4 * q, lane)] = v.x;
      A[SW(4 + 4 * q, lane)] = v.y;
      A[SW(5 + 4 * q, lane)] = v.z;
      A[SW(6 + 4 * q, lane)] = v.w;
    }
  } else {
    const int k = lane - 32;
    const int n = nb[k];
    const float4* f = (const float4*)(featT + ((size_t)b * NPTS + n) * 32);
#pragma unroll
    for (int q = 4; q < 8; ++q) {
      float4 v = f[q];
      A[SW(3 + 4 * q, k)] = v.x;
      A[SW(4 + 4 * q, k)] = v.y;
      A[SW(5 + 4 * q, k)] = v.z;
      A[SW(6 + 4 * q, k)] = v.w;
    }
  }
  __syncthreads();
  float acc[4][8];
  layerT(A, Wt, 64, 35, *(const float4*)(b1 + 4 * og), og, kg, acc);
  storeT(Bf, og, kg, acc);
  __syncthreads();
  layerT(Bf, Wt + 2240, 64, 64, *(const float4*)(b2 + 4 * og), og, kg, acc);
  storeT(A, og, kg, acc);
  __syncthreads();
  float* outp = outT + (size_t)g * 128;
#pragma unroll 1
  for (int h = 0; h < 2; ++h) {
    layerT(A, Wt + 6336 + 64 * h, 128, 64, *(const float4*)(b3 + 64 * h + 4 * og), og,
           kg, acc);
    float4 res;
    float* rp = (float*)&res;
#pragma unroll
    for (int oi = 0; oi < 4; ++oi) {
      float m = 0.f;
#pragma unroll
      for (int ki = 0; ki < 8; ++ki) m = fmaxf(m, acc[oi][ki]);
      m = fmaxf(m, __shfl_xor(m, 16));
      m = fmaxf(m, __shfl_xor(m, 32));
      rp[oi] = m;
    }
    if (kg == 0) *(float4*)(outp + 64 * h + 4 * og) = res;
  }
}

// ---------- output transpose (B,M,128) -> (B,128,M) ----------
__global__ __launch_bounds__(256) void outT_kernel(const float* __restrict__ outT,
                                                   float* __restrict__ out) {
  const int bid = blockIdx.x;
  const int b = bid >> 8;
  const int r = bid & 255;
  const int o0 = (r >> 6) * 32;
  const int m0 = (r & 63) * 32;
  __shared__ float tile[32][33];
  const int tx = threadIdx.x & 31, ty = threadIdx.x >> 5;
  const float* src = outT + ((size_t)b * MCTR + m0) * 128;
#pragma unroll
  for (int s = 0; s < 4; ++s) {
    int m = ty + 8 * s;
    tile[m][tx] = src[(size_t)m * 128 + o0 + tx];
  }
  __syncthreads();
  float* dst = out + ((size_t)b * 128 + o0) * MCTR + m0;
#pragma unroll
  for (int s = 0; s < 4; ++s) {
    int o = ty + 8 * s;
    dst[(size_t)o * MCTR + tx] = tile[tx][o];
  }
}

extern "C" void kernel_launch(void* const* d_in, const int* in_sizes, int n_in,
                              void* d_out, int out_size, void* d_ws, size_t ws_size,
                              hipStream_t stream) {
  (void)in_sizes; (void)n_in; (void)out_size; (void)ws_size;
  const float* feats = (const float*)d_in[0];
  const float* coords = (const float*)d_in[1];
  const float* W1 = (const float*)d_in[2];
  const float* b1 = (const float*)d_in[3];
  const float* W2 = (const float*)d_in[4];
  const float* b2 = (const float*)d_in[5];
  const float* W3 = (const float*)d_in[6];
  const float* b3 = (const float*)d_in[7];
  float* out = (float*)d_out;
  float* centers = out + (size_t)BATCH * 128 * MCTR;

  float* ws_f = (float*)d_ws;
  float* featT = ws_f;                                     // 1,048,576 f
  float* Wt = ws_f + 1048576;                              //    14,528 f
  int* cidx = (int*)(ws_f + 1048576 + 14528);              //     8,192 i
  int* nbidx = (int*)(ws_f + 1048576 + 14528 + 8192);      //   262,144 i
  float* outTbuf = ws_f + 1048576 + 14528 + 8192 + 262144; // 1,048,576 f
  // sorted-coord arrays overlay outTbuf: dead before mlp_kernel writes it
  float* sX = outTbuf;                 // 32768 f
  float* sY = outTbuf + 32768;         // 32768 f
  float* sZ = outTbuf + 65536;         // 32768 f
  int* sOrig = (int*)(outTbuf + 98304);// 32768 i

  featT_kernel<<<1024, 256, 0, stream>>>(feats, featT);
  prep_kernel<<<32, 256, 0, stream>>>(W1, W2, W3, Wt);
  xsort_kernel<<<BATCH, 512, 0, stream>>>(coords, sX, sY, sZ, sOrig);
  fps_kernel<<<BATCH, 512, 0, stream>>>(sX, sY, sZ, sOrig, cidx, centers);
  ballq_kernel<<<2048, 256, 0, stream>>>(coords, cidx, nbidx);
  mlp_kernel<<<BATCH * MCTR, 64, 0, stream>>>(coords, featT, Wt, b1, b2, b3, cidx, nbidx, outTbuf);
  outT_kernel<<<1024, 256, 0, stream>>>(outTbuf, out);
}